// Round 1
// baseline (554.230 us; speedup 1.0000x reference)
//
#include <hip/hip_runtime.h>

using short8 = __attribute__((ext_vector_type(8))) short;
using f32x4  = __attribute__((ext_vector_type(4))) float;
using u16x4  = __attribute__((ext_vector_type(4))) unsigned short;
using fl4    = __attribute__((ext_vector_type(4))) float;

#define MFMA16(a, b, c) __builtin_amdgcn_mfma_f32_16x16x32_bf16((a), (b), (c), 0, 0, 0)

static __device__ __forceinline__ unsigned short f2bf(float f) {
  union { float f; unsigned u; } x; x.f = f;
  return (unsigned short)((x.u + 0x7FFFu + ((x.u >> 16) & 1u)) >> 16);
}
static __device__ __forceinline__ float bf2f(unsigned short s) {
  union { unsigned u; float f; } x; x.u = ((unsigned)s) << 16;
  return x.f;
}

// ---------------------------------------------------------------------------
// Wt[n][k] = bf16(W[k][n])  (weights transposed so B-fragments are k-contiguous)
// ---------------------------------------------------------------------------
__global__ __launch_bounds__(256) void k_wconv(const float* __restrict__ W,
                                               unsigned short* __restrict__ Wt) {
  __shared__ float tile[64][65];
  const int t = threadIdx.x;
  const int n0 = blockIdx.x * 64, k0 = blockIdx.y * 64;
#pragma unroll
  for (int p = 0; p < 4; ++p) {
    int row = p * 16 + (t >> 4);  // k-local
    int c4 = (t & 15) * 4;        // n-local
    fl4 val = *(const fl4*)&W[(size_t)(k0 + row) * 1024 + n0 + c4];
    tile[row][c4 + 0] = val[0];
    tile[row][c4 + 1] = val[1];
    tile[row][c4 + 2] = val[2];
    tile[row][c4 + 3] = val[3];
  }
  __syncthreads();
#pragma unroll
  for (int p = 0; p < 4; ++p) {
    int n = p * 16 + (t >> 4);
    int k4 = (t & 15) * 4;
    u16x4 u;
    u[0] = f2bf(tile[k4 + 0][n]);
    u[1] = f2bf(tile[k4 + 1][n]);
    u[2] = f2bf(tile[k4 + 2][n]);
    u[3] = f2bf(tile[k4 + 3][n]);
    *(u16x4*)&Wt[(size_t)(n0 + n) * 1024 + k0 + k4] = u;
  }
}

// ---------------------------------------------------------------------------
// Projections: QW = (q@Wq+bq)/8, KW = (v@Wk+bk), VWT = transpose of (v@Wv+bv)
// mode: 0=QW 1=KW 2=VWT. 128x128 tile, BK=32, 4 waves (2x2 of 64x64).
// ---------------------------------------------------------------------------
__global__ __launch_bounds__(256) void k_proj(
    const float* __restrict__ q, const float* __restrict__ v,
    const unsigned short* __restrict__ WtQ, const unsigned short* __restrict__ WtK,
    const unsigned short* __restrict__ WtV,
    const float* __restrict__ bq, const float* __restrict__ bk,
    const float* __restrict__ bv,
    unsigned short* __restrict__ QW, unsigned short* __restrict__ KW,
    unsigned short* __restrict__ VWT) {
  const int mode = blockIdx.z;
  const float* A = (mode == 0) ? q : v;
  const unsigned short* Wt = (mode == 0) ? WtQ : (mode == 1) ? WtK : WtV;
  const float* bias = (mode == 0) ? bq : (mode == 1) ? bk : bv;
  const int n0 = blockIdx.x * 128, m0 = blockIdx.y * 128;
  const int t = threadIdx.x, lane = t & 63, w = t >> 6;
  const int g = lane >> 4, ln = lane & 15;
  const int wm = w >> 1, wn = w & 1;
  __shared__ unsigned short sm[16896];
  unsigned short* a_lds = sm;         // [128][40]
  unsigned short* b_lds = sm + 5120;  // [128][40]
  f32x4 acc[4][4] = {};
  for (int kk = 0; kk < 1024; kk += 32) {
    __syncthreads();
#pragma unroll
    for (int p = 0; p < 4; ++p) {
      int i4 = p * 256 + t;
      int row = i4 >> 3, c4 = (i4 & 7) * 4;
      fl4 val = *(const fl4*)&A[(size_t)(m0 + row) * 1024 + kk + c4];
      u16x4 u;
      u[0] = f2bf(val[0]); u[1] = f2bf(val[1]);
      u[2] = f2bf(val[2]); u[3] = f2bf(val[3]);
      *(u16x4*)&a_lds[row * 40 + c4] = u;
    }
#pragma unroll
    for (int p = 0; p < 4; ++p) {
      int i4 = p * 256 + t;
      int row = i4 >> 3, c4 = (i4 & 7) * 4;
      *(u16x4*)&b_lds[row * 40 + c4] =
          *(const u16x4*)&Wt[(size_t)(n0 + row) * 1024 + kk + c4];
    }
    __syncthreads();
    short8 af[4];
#pragma unroll
    for (int fm = 0; fm < 4; ++fm)
      af[fm] = *(const short8*)&a_lds[(wm * 64 + fm * 16 + ln) * 40 + 8 * g];
#pragma unroll
    for (int fn = 0; fn < 4; ++fn) {
      short8 bfr = *(const short8*)&b_lds[(wn * 64 + fn * 16 + ln) * 40 + 8 * g];
#pragma unroll
      for (int fm = 0; fm < 4; ++fm) acc[fm][fn] = MFMA16(af[fm], bfr, acc[fm][fn]);
    }
  }
  __syncthreads();
  const float scale = (mode == 0) ? 0.125f : 1.0f;
#pragma unroll
  for (int fn = 0; fn < 4; ++fn) {
    float bn = bias[n0 + wn * 64 + fn * 16 + ln];
#pragma unroll
    for (int fm = 0; fm < 4; ++fm) {
#pragma unroll
      for (int r = 0; r < 4; ++r) {
        float val = (acc[fm][fn][r] + bn) * scale;
        sm[(wm * 64 + fm * 16 + 4 * g + r) * 132 + wn * 64 + fn * 16 + ln] = f2bf(val);
      }
    }
  }
  __syncthreads();
  if (mode < 2) {
    unsigned short* OUT = (mode == 0) ? QW : KW;
#pragma unroll
    for (int p = 0; p < 16; ++p) {
      int row = p * 8 + (t >> 5), c4 = (t & 31) * 4;
      *(u16x4*)&OUT[(size_t)(m0 + row) * 1024 + n0 + c4] =
          *(const u16x4*)&sm[row * 132 + c4];
    }
  } else {
    const int b = m0 >> 10, s0 = m0 & 1023;
#pragma unroll
    for (int p = 0; p < 16; ++p) {
#pragma unroll
      for (int qh = 0; qh < 2; ++qh) {
        int hdl = p * 8 + (t >> 5);
        int sl = qh * 64 + (t & 31) * 2;
        unsigned lo = sm[sl * 132 + hdl];
        unsigned hi = sm[(sl + 1) * 132 + hdl];
        int hd = n0 + hdl;
        int h = hd >> 6, d = hd & 63;
        *(unsigned*)&VWT[((size_t)(b * 16 + h) * 64 + d) * 1024 + s0 + sl] =
            lo | (hi << 16);
      }
    }
  }
}

// ---------------------------------------------------------------------------
// Position-bias scores for one j: CB[bh][jl][k] = sum_d QW[b,j,h,d]*pb[j,k,d]
// (QW already carries the 1/8 scale). M=bh(128), N=k(128 tile), K=d(64).
// ---------------------------------------------------------------------------
__global__ __launch_bounds__(256) void k_pbias(
    const unsigned short* __restrict__ QW, const float* __restrict__ pb,
    unsigned short* __restrict__ CB, int jbase) {
  const int kt = blockIdx.x;  // 0..7
  const int jl = blockIdx.y;  // 0..127
  const int j = jbase + jl;
  const int t = threadIdx.x, lane = t & 63, w = t >> 6;
  const int g = lane >> 4, ln = lane & 15;
  const int wm = w >> 1, wn = w & 1;
  __shared__ unsigned short sm[18432];
  unsigned short* a_lds = sm;         // [128 bh][72]
  unsigned short* b_lds = sm + 9216;  // [128 k][72]
#pragma unroll
  for (int p = 0; p < 8; ++p) {
    int i4 = p * 256 + t;
    int row = i4 >> 4, c4 = (i4 & 15) * 4;
    *(u16x4*)&a_lds[row * 72 + c4] =
        *(const u16x4*)&QW[((size_t)(row >> 4) * 1024 + j) * 1024 + (row & 15) * 64 + c4];
  }
#pragma unroll
  for (int p = 0; p < 8; ++p) {
    int i4 = p * 256 + t;
    int row = i4 >> 4, c4 = (i4 & 15) * 4;
    fl4 val = *(const fl4*)&pb[((size_t)j * 1024 + kt * 128 + row) * 64 + c4];
    u16x4 u;
    u[0] = f2bf(val[0]); u[1] = f2bf(val[1]);
    u[2] = f2bf(val[2]); u[3] = f2bf(val[3]);
    *(u16x4*)&b_lds[row * 72 + c4] = u;
  }
  __syncthreads();
  f32x4 acc[4][4] = {};
#pragma unroll
  for (int ks = 0; ks < 2; ++ks) {
    short8 af[4];
#pragma unroll
    for (int fm = 0; fm < 4; ++fm)
      af[fm] = *(const short8*)&a_lds[(wm * 64 + fm * 16 + ln) * 72 + ks * 32 + 8 * g];
#pragma unroll
    for (int fn = 0; fn < 4; ++fn) {
      short8 bfr = *(const short8*)&b_lds[(wn * 64 + fn * 16 + ln) * 72 + ks * 32 + 8 * g];
#pragma unroll
      for (int fm = 0; fm < 4; ++fm) acc[fm][fn] = MFMA16(af[fm], bfr, acc[fm][fn]);
    }
  }
  __syncthreads();
#pragma unroll
  for (int fn = 0; fn < 4; ++fn) {
#pragma unroll
    for (int fm = 0; fm < 4; ++fm) {
#pragma unroll
      for (int r = 0; r < 4; ++r)
        sm[(wm * 64 + fm * 16 + 4 * g + r) * 132 + wn * 64 + fn * 16 + ln] =
            f2bf(acc[fm][fn][r]);
    }
  }
  __syncthreads();
#pragma unroll
  for (int p = 0; p < 16; ++p) {
    int row = p * 8 + (t >> 5), c4 = (t & 31) * 4;
    *(u16x4*)&CB[((size_t)row * 128 + jl) * 1024 + kt * 128 + c4] =
        *(const u16x4*)&sm[row * 132 + c4];
  }
}

// ---------------------------------------------------------------------------
// Flash attention per (b, h, 64-row j-tile). Scores MFMA-initialized from CB.
// 4 waves, each owns 16 j-rows. Online softmax over 8 k-tiles of 128.
// ---------------------------------------------------------------------------
__global__ __launch_bounds__(256) void k_attn(
    const unsigned short* __restrict__ QW, const unsigned short* __restrict__ KW,
    const unsigned short* __restrict__ VWT, const unsigned short* __restrict__ CB,
    const int* __restrict__ vmask, unsigned short* __restrict__ OB, int jbase) {
  const int jt = blockIdx.x, h = blockIdx.y, b = blockIdx.z;
  const int t = threadIdx.x, lane = t & 63, w = t >> 6;
  const int g = lane >> 4, ln = lane & 15;
  const int j0 = jbase + jt * 64;  // global j of block
  const int jl0 = jt * 64;         // stripe-local j
  __shared__ unsigned short lds_k[128 * 72];   // [k 128][d 72]
  __shared__ unsigned short lds_vt[64 * 136];  // [d 64][k 136]
  __shared__ unsigned short lds_p[4 * 16 * 136];
  unsigned short* pw = &lds_p[w * (16 * 136)];
  short8 qf[2];
  {
    const size_t qrow = ((size_t)b * 1024 + (j0 + w * 16 + ln)) * 1024 + h * 64;
    qf[0] = *(const short8*)&QW[qrow + 8 * g];
    qf[1] = *(const short8*)&QW[qrow + 32 + 8 * g];
  }
  f32x4 o_acc[4] = {};
  float m_run[4], l_run[4];
#pragma unroll
  for (int r = 0; r < 4; ++r) { m_run[r] = -1e30f; l_run[r] = 0.f; }

  for (int kt = 0; kt < 8; ++kt) {
    __syncthreads();
#pragma unroll
    for (int p = 0; p < 8; ++p) {
      int i4 = p * 256 + t;
      int row = i4 >> 4, c4 = (i4 & 15) * 4;
      *(u16x4*)&lds_k[row * 72 + c4] =
          *(const u16x4*)&KW[((size_t)b * 1024 + kt * 128 + row) * 1024 + h * 64 + c4];
    }
#pragma unroll
    for (int p = 0; p < 8; ++p) {
      int i4 = p * 256 + t;
      int row = i4 >> 5, c4 = (i4 & 31) * 4;
      *(u16x4*)&lds_vt[row * 136 + c4] =
          *(const u16x4*)&VWT[(((size_t)b * 16 + h) * 64 + row) * 1024 + kt * 128 + c4];
    }
    __syncthreads();
    f32x4 s[8];
#pragma unroll
    for (int fn = 0; fn < 8; ++fn) {
#pragma unroll
      for (int r = 0; r < 4; ++r) {
        s[fn][r] = bf2f(CB[(((size_t)b * 16 + h) * 128 + (jl0 + w * 16 + 4 * g + r)) * 1024 +
                           kt * 128 + ln + 16 * fn]);
      }
    }
#pragma unroll
    for (int ks = 0; ks < 2; ++ks) {
#pragma unroll
      for (int fn = 0; fn < 8; ++fn) {
        short8 bfr = *(const short8*)&lds_k[(ln + 16 * fn) * 72 + ks * 32 + 8 * g];
        s[fn] = MFMA16(qf[ks], bfr, s[fn]);
      }
    }
#pragma unroll
    for (int fn = 0; fn < 8; ++fn) {
      int vm = vmask[b * 1024 + kt * 128 + ln + 16 * fn];
      float sub = (1.0f - (float)vm) * 1e12f;
#pragma unroll
      for (int r = 0; r < 4; ++r) s[fn][r] -= sub;
    }
    float mnew[4];
#pragma unroll
    for (int r = 0; r < 4; ++r) {
      mnew[r] = s[0][r];
#pragma unroll
      for (int fn = 1; fn < 8; ++fn) mnew[r] = fmaxf(mnew[r], s[fn][r]);
    }
#pragma unroll
    for (int off = 1; off < 16; off <<= 1) {
#pragma unroll
      for (int r = 0; r < 4; ++r) mnew[r] = fmaxf(mnew[r], __shfl_xor(mnew[r], off, 16));
    }
    float alpha[4], rs[4];
#pragma unroll
    for (int r = 0; r < 4; ++r) {
      float mt = fmaxf(m_run[r], mnew[r]);
      alpha[r] = __expf(m_run[r] - mt);
      m_run[r] = mt;
      rs[r] = 0.f;
    }
#pragma unroll
    for (int fn = 0; fn < 8; ++fn) {
#pragma unroll
      for (int r = 0; r < 4; ++r) {
        float pv = __expf(s[fn][r] - m_run[r]);
        s[fn][r] = pv;
        rs[r] += pv;
      }
    }
#pragma unroll
    for (int off = 1; off < 16; off <<= 1) {
#pragma unroll
      for (int r = 0; r < 4; ++r) rs[r] += __shfl_xor(rs[r], off, 16);
    }
#pragma unroll
    for (int r = 0; r < 4; ++r) l_run[r] = l_run[r] * alpha[r] + rs[r];
#pragma unroll
    for (int fn = 0; fn < 4; ++fn) {
#pragma unroll
      for (int r = 0; r < 4; ++r) o_acc[fn][r] *= alpha[r];
    }
    // P -> per-wave LDS -> A-fragments
#pragma unroll
    for (int fn = 0; fn < 8; ++fn) {
#pragma unroll
      for (int r = 0; r < 4; ++r)
        pw[(4 * g + r) * 136 + ln + 16 * fn] = f2bf(s[fn][r]);
    }
    asm volatile("s_waitcnt lgkmcnt(0)" ::: "memory");
#pragma unroll
    for (int ks = 0; ks < 4; ++ks) {
      short8 ap = *(const short8*)&pw[ln * 136 + ks * 32 + 8 * g];
#pragma unroll
      for (int fn = 0; fn < 4; ++fn) {
        short8 bv = *(const short8*)&lds_vt[(ln + 16 * fn) * 136 + ks * 32 + 8 * g];
        o_acc[fn] = MFMA16(ap, bv, o_acc[fn]);
      }
    }
  }
#pragma unroll
  for (int r = 0; r < 4; ++r) {
    float inv = 1.0f / l_run[r];
#pragma unroll
    for (int fn = 0; fn < 4; ++fn) o_acc[fn][r] *= inv;
  }
  // bounce o through per-wave LDS for vectorized store
#pragma unroll
  for (int fn = 0; fn < 4; ++fn) {
#pragma unroll
    for (int r = 0; r < 4; ++r)
      pw[(4 * g + r) * 136 + ln + 16 * fn] = f2bf(o_acc[fn][r]);
  }
  asm volatile("s_waitcnt lgkmcnt(0)" ::: "memory");
#pragma unroll
  for (int p = 0; p < 4; ++p) {
    int idx = p * 64 + lane;
    int row = idx >> 4, c4 = (idx & 15) * 4;
    *(u16x4*)&OB[((size_t)b * 1024 + (j0 + w * 16 + row)) * 1024 + h * 64 + c4] =
        *(const u16x4*)&pw[row * 136 + c4];
  }
}

// ---------------------------------------------------------------------------
// Output projection: out = (OB @ Wo + bo) * q_mask  (f32 out)
// ---------------------------------------------------------------------------
__global__ __launch_bounds__(256) void k_out(
    const unsigned short* __restrict__ OB, const unsigned short* __restrict__ WtO,
    const float* __restrict__ bo, const int* __restrict__ qmask,
    float* __restrict__ out) {
  const int n0 = blockIdx.x * 128, m0 = blockIdx.y * 128;
  const int t = threadIdx.x, lane = t & 63, w = t >> 6;
  const int g = lane >> 4, ln = lane & 15;
  const int wm = w >> 1, wn = w & 1;
  __shared__ unsigned short sm[10240];
  unsigned short* a_lds = sm;
  unsigned short* b_lds = sm + 5120;
  f32x4 acc[4][4] = {};
  for (int kk = 0; kk < 1024; kk += 32) {
    __syncthreads();
#pragma unroll
    for (int p = 0; p < 4; ++p) {
      int i4 = p * 256 + t;
      int row = i4 >> 3, c4 = (i4 & 7) * 4;
      *(u16x4*)&a_lds[row * 40 + c4] =
          *(const u16x4*)&OB[(size_t)(m0 + row) * 1024 + kk + c4];
    }
#pragma unroll
    for (int p = 0; p < 4; ++p) {
      int i4 = p * 256 + t;
      int row = i4 >> 3, c4 = (i4 & 7) * 4;
      *(u16x4*)&b_lds[row * 40 + c4] =
          *(const u16x4*)&WtO[(size_t)(n0 + row) * 1024 + kk + c4];
    }
    __syncthreads();
    short8 af[4];
#pragma unroll
    for (int fm = 0; fm < 4; ++fm)
      af[fm] = *(const short8*)&a_lds[(wm * 64 + fm * 16 + ln) * 40 + 8 * g];
#pragma unroll
    for (int fn = 0; fn < 4; ++fn) {
      short8 bfr = *(const short8*)&b_lds[(wn * 64 + fn * 16 + ln) * 40 + 8 * g];
#pragma unroll
      for (int fm = 0; fm < 4; ++fm) acc[fm][fn] = MFMA16(af[fm], bfr, acc[fm][fn]);
    }
  }
  float bn[4];
#pragma unroll
  for (int fn = 0; fn < 4; ++fn) bn[fn] = bo[n0 + wn * 64 + fn * 16 + ln];
#pragma unroll
  for (int fm = 0; fm < 4; ++fm) {
#pragma unroll
    for (int r = 0; r < 4; ++r) {
      int row = m0 + wm * 64 + fm * 16 + 4 * g + r;
      float qm = (float)qmask[row];
#pragma unroll
      for (int fn = 0; fn < 4; ++fn)
        out[(size_t)row * 1024 + n0 + wn * 64 + fn * 16 + ln] =
            (acc[fm][fn][r] + bn[fn]) * qm;
    }
  }
}

// ---------------------------------------------------------------------------
extern "C" void kernel_launch(void* const* d_in, const int* in_sizes, int n_in,
                              void* d_out, int out_size, void* d_ws, size_t ws_size,
                              hipStream_t stream) {
  const float* q  = (const float*)d_in[0];
  // d_in[1] = k  -- intentionally unused (reference projects K from v)
  const float* v  = (const float*)d_in[2];
  const float* pb = (const float*)d_in[3];
  const float* Wq = (const float*)d_in[4];
  const float* Wk = (const float*)d_in[5];
  const float* Wv = (const float*)d_in[6];
  const float* Wo = (const float*)d_in[7];
  const float* bq = (const float*)d_in[8];
  const float* bk = (const float*)d_in[9];
  const float* bv = (const float*)d_in[10];
  const float* bo = (const float*)d_in[11];
  const int* qm = (const int*)d_in[12];
  const int* vm = (const int*)d_in[13];
  float* out = (float*)d_out;

  unsigned short* ws = (unsigned short*)d_ws;
  unsigned short* WTQ = ws;                     // 1M elems each
  unsigned short* WTK = WTQ + 1024 * 1024;
  unsigned short* WTV = WTK + 1024 * 1024;
  unsigned short* WTO = WTV + 1024 * 1024;
  unsigned short* QW  = WTO + 1024 * 1024;      // [8192][1024], pre-scaled by 1/8
  unsigned short* KW  = QW + 8192 * 1024;       // [8192][1024]
  unsigned short* VWT = KW + 8192 * 1024;       // [b][h][d][s]
  unsigned short* OB  = VWT + 8192 * 1024;      // [8192][1024]
  unsigned short* CB  = OB + 8192 * 1024;       // [bh 128][jl 128][k 1024] stripe
  // total ws: ~104 MB

  k_wconv<<<dim3(16, 16), 256, 0, stream>>>(Wq, WTQ);
  k_wconv<<<dim3(16, 16), 256, 0, stream>>>(Wk, WTK);
  k_wconv<<<dim3(16, 16), 256, 0, stream>>>(Wv, WTV);
  k_wconv<<<dim3(16, 16), 256, 0, stream>>>(Wo, WTO);
  k_proj<<<dim3(8, 64, 3), 256, 0, stream>>>(q, v, WTQ, WTK, WTV, bq, bk, bv,
                                             QW, KW, VWT);
  for (int st = 0; st < 8; ++st) {
    k_pbias<<<dim3(8, 128), 256, 0, stream>>>(QW, pb, CB, st * 128);
    k_attn<<<dim3(2, 16, 8), 256, 0, stream>>>(QW, KW, VWT, CB, vm, OB, st * 128);
  }
  k_out<<<dim3(8, 64), 256, 0, stream>>>(OB, WTO, bo, qm, out);
}

// Round 2
// 523.172 us; speedup vs baseline: 1.0594x; 1.0594x over previous
//
#include <hip/hip_runtime.h>

using short8 = __attribute__((ext_vector_type(8))) short;
using f32x4  = __attribute__((ext_vector_type(4))) float;
using u16x4  = __attribute__((ext_vector_type(4))) unsigned short;
using fl4    = __attribute__((ext_vector_type(4))) float;

#define MFMA16(a, b, c) __builtin_amdgcn_mfma_f32_16x16x32_bf16((a), (b), (c), 0, 0, 0)

static __device__ __forceinline__ unsigned short f2bf(float f) {
  union { float f; unsigned u; } x; x.f = f;
  return (unsigned short)((x.u + 0x7FFFu + ((x.u >> 16) & 1u)) >> 16);
}
static __device__ __forceinline__ float bf2f(unsigned short s) {
  union { unsigned u; float f; } x; x.u = ((unsigned)s) << 16;
  return x.f;
}

// async global->LDS, 16B per lane; lds base must be wave-uniform.
static __device__ __forceinline__ void gload16(const void* g, void* l) {
  __builtin_amdgcn_global_load_lds((const __attribute__((address_space(1))) void*)g,
                                   (__attribute__((address_space(3))) void*)l, 16, 0, 0);
}

// ---------------------------------------------------------------------------
// Wt[n][k] = bf16(W[k][n])
// ---------------------------------------------------------------------------
__global__ __launch_bounds__(256) void k_wconv(const float* __restrict__ W,
                                               unsigned short* __restrict__ Wt) {
  __shared__ float tile[64][65];
  const int t = threadIdx.x;
  const int n0 = blockIdx.x * 64, k0 = blockIdx.y * 64;
#pragma unroll
  for (int p = 0; p < 4; ++p) {
    int row = p * 16 + (t >> 4);
    int c4 = (t & 15) * 4;
    fl4 val = *(const fl4*)&W[(size_t)(k0 + row) * 1024 + n0 + c4];
    tile[row][c4 + 0] = val[0];
    tile[row][c4 + 1] = val[1];
    tile[row][c4 + 2] = val[2];
    tile[row][c4 + 3] = val[3];
  }
  __syncthreads();
#pragma unroll
  for (int p = 0; p < 4; ++p) {
    int n = p * 16 + (t >> 4);
    int k4 = (t & 15) * 4;
    u16x4 u;
    u[0] = f2bf(tile[k4 + 0][n]);
    u[1] = f2bf(tile[k4 + 1][n]);
    u[2] = f2bf(tile[k4 + 2][n]);
    u[3] = f2bf(tile[k4 + 3][n]);
    *(u16x4*)&Wt[(size_t)(n0 + n) * 1024 + k0 + k4] = u;
  }
}

// ---------------------------------------------------------------------------
// f32 -> bf16 bulk convert (q and v), 8 elems/thread
// ---------------------------------------------------------------------------
__global__ __launch_bounds__(256) void k_cvt(const float* __restrict__ a,
                                             const float* __restrict__ b,
                                             unsigned short* __restrict__ oa,
                                             unsigned short* __restrict__ ob) {
  const float* src = blockIdx.y ? b : a;
  unsigned short* dst = blockIdx.y ? ob : oa;
  size_t i = ((size_t)blockIdx.x * 256 + threadIdx.x) * 8;
  fl4 v0 = *(const fl4*)&src[i];
  fl4 v1 = *(const fl4*)&src[i + 4];
  u16x4 u0, u1;
  u0[0] = f2bf(v0[0]); u0[1] = f2bf(v0[1]); u0[2] = f2bf(v0[2]); u0[3] = f2bf(v0[3]);
  u1[0] = f2bf(v1[0]); u1[1] = f2bf(v1[1]); u1[2] = f2bf(v1[2]); u1[3] = f2bf(v1[3]);
  *(u16x4*)&dst[i] = u0;
  *(u16x4*)&dst[i + 4] = u1;
}

// ---------------------------------------------------------------------------
// m97-style bf16 GEMM for projections. mode: 0=QW(scaled 1/8) 1=KW 2=VWT.
// 128x128 tile, BK=64, global_load_lds(16) staging, 4 waves 2x2.
// ---------------------------------------------------------------------------
__global__ __launch_bounds__(256) void k_proj2(
    const unsigned short* __restrict__ QB, const unsigned short* __restrict__ VB,
    const unsigned short* __restrict__ WtQ, const unsigned short* __restrict__ WtK,
    const unsigned short* __restrict__ WtV,
    const float* __restrict__ bq, const float* __restrict__ bk,
    const float* __restrict__ bv,
    unsigned short* __restrict__ QW, unsigned short* __restrict__ KW,
    unsigned short* __restrict__ VWT) {
  const int mode = blockIdx.z;
  const unsigned short* A8 = (mode == 0) ? QB : VB;
  const unsigned short* Wt = (mode == 0) ? WtQ : (mode == 1) ? WtK : WtV;
  const float* bias = (mode == 0) ? bq : (mode == 1) ? bk : bv;
  const int n0 = blockIdx.x * 128, m0 = blockIdx.y * 128;
  const int t = threadIdx.x, lane = t & 63, w = t >> 6;
  const int g = lane >> 4, ln = lane & 15;
  const int wm = w >> 1, wn = w & 1;
  __shared__ unsigned short sh[16896];
  unsigned short* As = sh;          // [128][64] linear
  unsigned short* Bs = sh + 8192;   // [128][64] linear
  const int srow = lane >> 3;       // 0..7
  const int scol = (lane & 7) * 8;  // elems
  f32x4 acc[4][4] = {};
  for (int kk = 0; kk < 1024; kk += 64) {
    __syncthreads();
#pragma unroll
    for (int p = 0; p < 4; ++p) {
      gload16(&A8[(size_t)(m0 + p * 32 + w * 8 + srow) * 1024 + kk + scol],
              &As[p * 2048 + w * 512]);
      gload16(&Wt[(size_t)(n0 + p * 32 + w * 8 + srow) * 1024 + kk + scol],
              &Bs[p * 2048 + w * 512]);
    }
    __syncthreads();
#pragma unroll
    for (int ks = 0; ks < 2; ++ks) {
      short8 af[4];
#pragma unroll
      for (int fm = 0; fm < 4; ++fm)
        af[fm] = *(const short8*)&As[(wm * 64 + fm * 16 + ln) * 64 + ks * 32 + 8 * g];
#pragma unroll
      for (int fn = 0; fn < 4; ++fn) {
        short8 bfr = *(const short8*)&Bs[(wn * 64 + fn * 16 + ln) * 64 + ks * 32 + 8 * g];
#pragma unroll
        for (int fm = 0; fm < 4; ++fm) acc[fm][fn] = MFMA16(af[fm], bfr, acc[fm][fn]);
      }
    }
  }
  __syncthreads();
  const float scale = (mode == 0) ? 0.125f : 1.0f;
#pragma unroll
  for (int fn = 0; fn < 4; ++fn) {
    float bn = bias[n0 + wn * 64 + fn * 16 + ln];
#pragma unroll
    for (int fm = 0; fm < 4; ++fm) {
#pragma unroll
      for (int r = 0; r < 4; ++r) {
        float val = (acc[fm][fn][r] + bn) * scale;
        sh[(wm * 64 + fm * 16 + 4 * g + r) * 132 + wn * 64 + fn * 16 + ln] = f2bf(val);
      }
    }
  }
  __syncthreads();
  if (mode < 2) {
    unsigned short* OUT = (mode == 0) ? QW : KW;
#pragma unroll
    for (int p = 0; p < 16; ++p) {
      int row = p * 8 + (t >> 5), c4 = (t & 31) * 4;
      *(u16x4*)&OUT[(size_t)(m0 + row) * 1024 + n0 + c4] =
          *(const u16x4*)&sh[row * 132 + c4];
    }
  } else {
    const int b = m0 >> 10, s0 = m0 & 1023;
#pragma unroll
    for (int p = 0; p < 16; ++p) {
#pragma unroll
      for (int qh = 0; qh < 2; ++qh) {
        int hdl = p * 8 + (t >> 5);
        int sl = qh * 64 + (t & 31) * 2;
        unsigned lo = sh[sl * 132 + hdl];
        unsigned hi = sh[(sl + 1) * 132 + hdl];
        int hd = n0 + hdl;
        int h = hd >> 6, d = hd & 63;
        *(unsigned*)&VWT[((size_t)(b * 16 + h) * 64 + d) * 1024 + s0 + sl] =
            lo | (hi << 16);
      }
    }
  }
}

// ---------------------------------------------------------------------------
// Position-bias scores for one j: CB[bh][jl][k] = sum_d QW[b,j,h,d]*pb[j,k,d]
// ---------------------------------------------------------------------------
__global__ __launch_bounds__(256) void k_pbias(
    const unsigned short* __restrict__ QW, const float* __restrict__ pb,
    unsigned short* __restrict__ CB, int jbase) {
  const int kt = blockIdx.x;  // 0..7
  const int jl = blockIdx.y;  // 0..127
  const int j = jbase + jl;
  const int t = threadIdx.x, lane = t & 63, w = t >> 6;
  const int g = lane >> 4, ln = lane & 15;
  const int wm = w >> 1, wn = w & 1;
  __shared__ unsigned short sm[18432];
  unsigned short* a_lds = sm;         // [128 bh][72]
  unsigned short* b_lds = sm + 9216;  // [128 k][72]
#pragma unroll
  for (int p = 0; p < 8; ++p) {
    int i4 = p * 256 + t;
    int row = i4 >> 4, c4 = (i4 & 15) * 4;
    *(u16x4*)&a_lds[row * 72 + c4] =
        *(const u16x4*)&QW[((size_t)(row >> 4) * 1024 + j) * 1024 + (row & 15) * 64 + c4];
  }
#pragma unroll
  for (int p = 0; p < 8; ++p) {
    int i4 = p * 256 + t;
    int row = i4 >> 4, c4 = (i4 & 15) * 4;
    fl4 val = *(const fl4*)&pb[((size_t)j * 1024 + kt * 128 + row) * 64 + c4];
    u16x4 u;
    u[0] = f2bf(val[0]); u[1] = f2bf(val[1]);
    u[2] = f2bf(val[2]); u[3] = f2bf(val[3]);
    *(u16x4*)&b_lds[row * 72 + c4] = u;
  }
  __syncthreads();
  f32x4 acc[4][4] = {};
#pragma unroll
  for (int ks = 0; ks < 2; ++ks) {
    short8 af[4];
#pragma unroll
    for (int fm = 0; fm < 4; ++fm)
      af[fm] = *(const short8*)&a_lds[(wm * 64 + fm * 16 + ln) * 72 + ks * 32 + 8 * g];
#pragma unroll
    for (int fn = 0; fn < 4; ++fn) {
      short8 bfr = *(const short8*)&b_lds[(wn * 64 + fn * 16 + ln) * 72 + ks * 32 + 8 * g];
#pragma unroll
      for (int fm = 0; fm < 4; ++fm) acc[fm][fn] = MFMA16(af[fm], bfr, acc[fm][fn]);
    }
  }
  __syncthreads();
#pragma unroll
  for (int fn = 0; fn < 4; ++fn) {
#pragma unroll
    for (int fm = 0; fm < 4; ++fm) {
#pragma unroll
      for (int r = 0; r < 4; ++r)
        sm[(wm * 64 + fm * 16 + 4 * g + r) * 132 + wn * 64 + fn * 16 + ln] =
            f2bf(acc[fm][fn][r]);
    }
  }
  __syncthreads();
#pragma unroll
  for (int p = 0; p < 16; ++p) {
    int row = p * 8 + (t >> 5), c4 = (t & 31) * 4;
    *(u16x4*)&CB[((size_t)row * 128 + jl) * 1024 + kt * 128 + c4] =
        *(const u16x4*)&sm[row * 132 + c4];
  }
}

// ---------------------------------------------------------------------------
// Flash attention per (b, h, 64-row j-tile), scores init from CB.
// ---------------------------------------------------------------------------
__global__ __launch_bounds__(256) void k_attn(
    const unsigned short* __restrict__ QW, const unsigned short* __restrict__ KW,
    const unsigned short* __restrict__ VWT, const unsigned short* __restrict__ CB,
    const int* __restrict__ vmask, unsigned short* __restrict__ OB, int jbase) {
  const int jt = blockIdx.x, h = blockIdx.y, b = blockIdx.z;
  const int t = threadIdx.x, lane = t & 63, w = t >> 6;
  const int g = lane >> 4, ln = lane & 15;
  const int j0 = jbase + jt * 64;
  const int jl0 = jt * 64;
  __shared__ unsigned short lds_k[128 * 72];
  __shared__ unsigned short lds_vt[64 * 136];
  __shared__ unsigned short lds_p[4 * 16 * 136];
  unsigned short* pw = &lds_p[w * (16 * 136)];
  short8 qf[2];
  {
    const size_t qrow = ((size_t)b * 1024 + (j0 + w * 16 + ln)) * 1024 + h * 64;
    qf[0] = *(const short8*)&QW[qrow + 8 * g];
    qf[1] = *(const short8*)&QW[qrow + 32 + 8 * g];
  }
  f32x4 o_acc[4] = {};
  float m_run[4], l_run[4];
#pragma unroll
  for (int r = 0; r < 4; ++r) { m_run[r] = -1e30f; l_run[r] = 0.f; }

  for (int kt = 0; kt < 8; ++kt) {
    __syncthreads();
#pragma unroll
    for (int p = 0; p < 8; ++p) {
      int i4 = p * 256 + t;
      int row = i4 >> 4, c4 = (i4 & 15) * 4;
      *(u16x4*)&lds_k[row * 72 + c4] =
          *(const u16x4*)&KW[((size_t)b * 1024 + kt * 128 + row) * 1024 + h * 64 + c4];
    }
#pragma unroll
    for (int p = 0; p < 8; ++p) {
      int i4 = p * 256 + t;
      int row = i4 >> 5, c4 = (i4 & 31) * 4;
      *(u16x4*)&lds_vt[row * 136 + c4] =
          *(const u16x4*)&VWT[(((size_t)b * 16 + h) * 64 + row) * 1024 + kt * 128 + c4];
    }
    __syncthreads();
    f32x4 s[8];
#pragma unroll
    for (int fn = 0; fn < 8; ++fn) {
#pragma unroll
      for (int r = 0; r < 4; ++r) {
        s[fn][r] = bf2f(CB[(((size_t)b * 16 + h) * 128 + (jl0 + w * 16 + 4 * g + r)) * 1024 +
                           kt * 128 + ln + 16 * fn]);
      }
    }
#pragma unroll
    for (int ks = 0; ks < 2; ++ks) {
#pragma unroll
      for (int fn = 0; fn < 8; ++fn) {
        short8 bfr = *(const short8*)&lds_k[(ln + 16 * fn) * 72 + ks * 32 + 8 * g];
        s[fn] = MFMA16(qf[ks], bfr, s[fn]);
      }
    }
#pragma unroll
    for (int fn = 0; fn < 8; ++fn) {
      int vm = vmask[b * 1024 + kt * 128 + ln + 16 * fn];
      float sub = (1.0f - (float)vm) * 1e12f;
#pragma unroll
      for (int r = 0; r < 4; ++r) s[fn][r] -= sub;
    }
    float mnew[4];
#pragma unroll
    for (int r = 0; r < 4; ++r) {
      mnew[r] = s[0][r];
#pragma unroll
      for (int fn = 1; fn < 8; ++fn) mnew[r] = fmaxf(mnew[r], s[fn][r]);
    }
#pragma unroll
    for (int off = 1; off < 16; off <<= 1) {
#pragma unroll
      for (int r = 0; r < 4; ++r) mnew[r] = fmaxf(mnew[r], __shfl_xor(mnew[r], off, 16));
    }
    float alpha[4], rs[4];
#pragma unroll
    for (int r = 0; r < 4; ++r) {
      float mt = fmaxf(m_run[r], mnew[r]);
      alpha[r] = __expf(m_run[r] - mt);
      m_run[r] = mt;
      rs[r] = 0.f;
    }
#pragma unroll
    for (int fn = 0; fn < 8; ++fn) {
#pragma unroll
      for (int r = 0; r < 4; ++r) {
        float pv = __expf(s[fn][r] - m_run[r]);
        s[fn][r] = pv;
        rs[r] += pv;
      }
    }
#pragma unroll
    for (int off = 1; off < 16; off <<= 1) {
#pragma unroll
      for (int r = 0; r < 4; ++r) rs[r] += __shfl_xor(rs[r], off, 16);
    }
#pragma unroll
    for (int r = 0; r < 4; ++r) l_run[r] = l_run[r] * alpha[r] + rs[r];
#pragma unroll
    for (int fn = 0; fn < 4; ++fn) {
#pragma unroll
      for (int r = 0; r < 4; ++r) o_acc[fn][r] *= alpha[r];
    }
#pragma unroll
    for (int fn = 0; fn < 8; ++fn) {
#pragma unroll
      for (int r = 0; r < 4; ++r)
        pw[(4 * g + r) * 136 + ln + 16 * fn] = f2bf(s[fn][r]);
    }
    asm volatile("s_waitcnt lgkmcnt(0)" ::: "memory");
#pragma unroll
    for (int ks = 0; ks < 4; ++ks) {
      short8 ap = *(const short8*)&pw[ln * 136 + ks * 32 + 8 * g];
#pragma unroll
      for (int fn = 0; fn < 4; ++fn) {
        short8 bv = *(const short8*)&lds_vt[(ln + 16 * fn) * 136 + ks * 32 + 8 * g];
        o_acc[fn] = MFMA16(ap, bv, o_acc[fn]);
      }
    }
  }
#pragma unroll
  for (int r = 0; r < 4; ++r) {
    float inv = 1.0f / l_run[r];
#pragma unroll
    for (int fn = 0; fn < 4; ++fn) o_acc[fn][r] *= inv;
  }
#pragma unroll
  for (int fn = 0; fn < 4; ++fn) {
#pragma unroll
    for (int r = 0; r < 4; ++r)
      pw[(4 * g + r) * 136 + ln + 16 * fn] = f2bf(o_acc[fn][r]);
  }
  asm volatile("s_waitcnt lgkmcnt(0)" ::: "memory");
#pragma unroll
  for (int p = 0; p < 4; ++p) {
    int idx = p * 64 + lane;
    int row = idx >> 4, c4 = (idx & 15) * 4;
    *(u16x4*)&OB[((size_t)b * 1024 + (j0 + w * 16 + row)) * 1024 + h * 64 + c4] =
        *(const u16x4*)&pw[row * 136 + c4];
  }
}

// ---------------------------------------------------------------------------
// Output projection (m97-style): out = (OB @ Wo + bo) * q_mask  (f32 out)
// ---------------------------------------------------------------------------
__global__ __launch_bounds__(256) void k_out2(
    const unsigned short* __restrict__ OB, const unsigned short* __restrict__ WtO,
    const float* __restrict__ bo, const int* __restrict__ qmask,
    float* __restrict__ out) {
  const int n0 = blockIdx.x * 128, m0 = blockIdx.y * 128;
  const int t = threadIdx.x, lane = t & 63, w = t >> 6;
  const int g = lane >> 4, ln = lane & 15;
  const int wm = w >> 1, wn = w & 1;
  __shared__ unsigned short sh[16384];
  unsigned short* As = sh;
  unsigned short* Bs = sh + 8192;
  const int srow = lane >> 3;
  const int scol = (lane & 7) * 8;
  f32x4 acc[4][4] = {};
  for (int kk = 0; kk < 1024; kk += 64) {
    __syncthreads();
#pragma unroll
    for (int p = 0; p < 4; ++p) {
      gload16(&OB[(size_t)(m0 + p * 32 + w * 8 + srow) * 1024 + kk + scol],
              &As[p * 2048 + w * 512]);
      gload16(&WtO[(size_t)(n0 + p * 32 + w * 8 + srow) * 1024 + kk + scol],
              &Bs[p * 2048 + w * 512]);
    }
    __syncthreads();
#pragma unroll
    for (int ks = 0; ks < 2; ++ks) {
      short8 af[4];
#pragma unroll
      for (int fm = 0; fm < 4; ++fm)
        af[fm] = *(const short8*)&As[(wm * 64 + fm * 16 + ln) * 64 + ks * 32 + 8 * g];
#pragma unroll
      for (int fn = 0; fn < 4; ++fn) {
        short8 bfr = *(const short8*)&Bs[(wn * 64 + fn * 16 + ln) * 64 + ks * 32 + 8 * g];
#pragma unroll
        for (int fm = 0; fm < 4; ++fm) acc[fm][fn] = MFMA16(af[fm], bfr, acc[fm][fn]);
      }
    }
  }
  float bn[4];
#pragma unroll
  for (int fn = 0; fn < 4; ++fn) bn[fn] = bo[n0 + wn * 64 + fn * 16 + ln];
#pragma unroll
  for (int fm = 0; fm < 4; ++fm) {
#pragma unroll
    for (int r = 0; r < 4; ++r) {
      int row = m0 + wm * 64 + fm * 16 + 4 * g + r;
      float qm = (float)qmask[row];
#pragma unroll
      for (int fn = 0; fn < 4; ++fn)
        out[(size_t)row * 1024 + n0 + wn * 64 + fn * 16 + ln] =
            (acc[fm][fn][r] + bn[fn]) * qm;
    }
  }
}

// ---------------------------------------------------------------------------
extern "C" void kernel_launch(void* const* d_in, const int* in_sizes, int n_in,
                              void* d_out, int out_size, void* d_ws, size_t ws_size,
                              hipStream_t stream) {
  const float* q  = (const float*)d_in[0];
  // d_in[1] = k  -- intentionally unused (reference projects K from v)
  const float* v  = (const float*)d_in[2];
  const float* pb = (const float*)d_in[3];
  const float* Wq = (const float*)d_in[4];
  const float* Wk = (const float*)d_in[5];
  const float* Wv = (const float*)d_in[6];
  const float* Wo = (const float*)d_in[7];
  const float* bq = (const float*)d_in[8];
  const float* bk = (const float*)d_in[9];
  const float* bv = (const float*)d_in[10];
  const float* bo = (const float*)d_in[11];
  const int* qm = (const int*)d_in[12];
  const int* vm = (const int*)d_in[13];
  float* out = (float*)d_out;

  unsigned short* ws = (unsigned short*)d_ws;
  const size_t M1 = 1024 * 1024;
  unsigned short* WTQ = ws;                    // 1M elems each
  unsigned short* WTK = WTQ + M1;
  unsigned short* WTV = WTK + M1;
  unsigned short* WTO = WTV + M1;
  unsigned short* QB  = WTO + M1;              // [8192][1024] bf16(q)
  unsigned short* VB  = QB + 8 * M1;           // [8192][1024] bf16(v)
  unsigned short* QW  = VB + 8 * M1;           // [8192][1024], pre-scaled 1/8
  unsigned short* KW  = QW + 8 * M1;
  unsigned short* VWT = KW + 8 * M1;           // [b][h][d][s]
  unsigned short* OB  = VWT + 8 * M1;
  unsigned short* CB  = OB + 8 * M1;           // [bh 128][jl 128][k 1024] stripe

  k_wconv<<<dim3(16, 16), 256, 0, stream>>>(Wq, WTQ);
  k_wconv<<<dim3(16, 16), 256, 0, stream>>>(Wk, WTK);
  k_wconv<<<dim3(16, 16), 256, 0, stream>>>(Wv, WTV);
  k_wconv<<<dim3(16, 16), 256, 0, stream>>>(Wo, WTO);
  k_cvt<<<dim3(4096, 2), 256, 0, stream>>>(q, v, QB, VB);
  k_proj2<<<dim3(8, 64, 3), 256, 0, stream>>>(QB, VB, WTQ, WTK, WTV, bq, bk, bv,
                                              QW, KW, VWT);
  for (int st = 0; st < 8; ++st) {
    k_pbias<<<dim3(8, 128), 256, 0, stream>>>(QW, pb, CB, st * 128);
    k_attn<<<dim3(2, 16, 8), 256, 0, stream>>>(QW, KW, VWT, CB, vm, OB, st * 128);
  }
  k_out2<<<dim3(8, 64), 256, 0, stream>>>(OB, WTO, bo, qm, out);
}

// Round 3
// 428.887 us; speedup vs baseline: 1.2923x; 1.2198x over previous
//
#include <hip/hip_runtime.h>

using short8 = __attribute__((ext_vector_type(8))) short;
using f32x4  = __attribute__((ext_vector_type(4))) float;
using u16x4  = __attribute__((ext_vector_type(4))) unsigned short;
using fl4    = __attribute__((ext_vector_type(4))) float;

#define MFMA16(a, b, c) __builtin_amdgcn_mfma_f32_16x16x32_bf16((a), (b), (c), 0, 0, 0)

static __device__ __forceinline__ unsigned short f2bf(float f) {
  union { float f; unsigned u; } x; x.f = f;
  return (unsigned short)((x.u + 0x7FFFu + ((x.u >> 16) & 1u)) >> 16);
}
static __device__ __forceinline__ float bf2f(unsigned short s) {
  union { unsigned u; float f; } x; x.u = ((unsigned)s) << 16;
  return x.f;
}

// async global->LDS, 16B per lane; lds base must be wave-uniform.
static __device__ __forceinline__ void gload16(const void* g, void* l) {
  __builtin_amdgcn_global_load_lds((const __attribute__((address_space(1))) void*)g,
                                   (__attribute__((address_space(3))) void*)l, 16, 0, 0);
}

// ---------------------------------------------------------------------------
// Wt[n][k] = bf16(W[k][n]) for 4 weight matrices (z picks which)
// ---------------------------------------------------------------------------
__global__ __launch_bounds__(256) void k_wconv4(
    const float* __restrict__ W0, const float* __restrict__ W1,
    const float* __restrict__ W2, const float* __restrict__ W3,
    unsigned short* __restrict__ Wt0, unsigned short* __restrict__ Wt1,
    unsigned short* __restrict__ Wt2, unsigned short* __restrict__ Wt3) {
  const float* W = (blockIdx.z == 0) ? W0 : (blockIdx.z == 1) ? W1
                   : (blockIdx.z == 2) ? W2 : W3;
  unsigned short* Wt = (blockIdx.z == 0) ? Wt0 : (blockIdx.z == 1) ? Wt1
                       : (blockIdx.z == 2) ? Wt2 : Wt3;
  __shared__ float tile[64][65];
  const int t = threadIdx.x;
  const int n0 = blockIdx.x * 64, k0 = blockIdx.y * 64;
#pragma unroll
  for (int p = 0; p < 4; ++p) {
    int row = p * 16 + (t >> 4);
    int c4 = (t & 15) * 4;
    fl4 val = *(const fl4*)&W[(size_t)(k0 + row) * 1024 + n0 + c4];
    tile[row][c4 + 0] = val[0];
    tile[row][c4 + 1] = val[1];
    tile[row][c4 + 2] = val[2];
    tile[row][c4 + 3] = val[3];
  }
  __syncthreads();
#pragma unroll
  for (int p = 0; p < 4; ++p) {
    int n = p * 16 + (t >> 4);
    int k4 = (t & 15) * 4;
    u16x4 u;
    u[0] = f2bf(tile[k4 + 0][n]);
    u[1] = f2bf(tile[k4 + 1][n]);
    u[2] = f2bf(tile[k4 + 2][n]);
    u[3] = f2bf(tile[k4 + 3][n]);
    *(u16x4*)&Wt[(size_t)(n0 + n) * 1024 + k0 + k4] = u;
  }
}

// ---------------------------------------------------------------------------
// f32 -> bf16 bulk convert (q and v)
// ---------------------------------------------------------------------------
__global__ __launch_bounds__(256) void k_cvt(const float* __restrict__ a,
                                             const float* __restrict__ b,
                                             unsigned short* __restrict__ oa,
                                             unsigned short* __restrict__ ob) {
  const float* src = blockIdx.y ? b : a;
  unsigned short* dst = blockIdx.y ? ob : oa;
  size_t i = ((size_t)blockIdx.x * 256 + threadIdx.x) * 8;
  fl4 v0 = *(const fl4*)&src[i];
  fl4 v1 = *(const fl4*)&src[i + 4];
  u16x4 u0, u1;
  u0[0] = f2bf(v0[0]); u0[1] = f2bf(v0[1]); u0[2] = f2bf(v0[2]); u0[3] = f2bf(v0[3]);
  u1[0] = f2bf(v1[0]); u1[1] = f2bf(v1[1]); u1[2] = f2bf(v1[2]); u1[3] = f2bf(v1[3]);
  *(u16x4*)&dst[i] = u0;
  *(u16x4*)&dst[i + 4] = u1;
}

// ---------------------------------------------------------------------------
// m97-style bf16 GEMM for projections. mode: 0=QW(scaled 1/8) 1=KW 2=VWT.
// ---------------------------------------------------------------------------
__global__ __launch_bounds__(256) void k_proj2(
    const unsigned short* __restrict__ QB, const unsigned short* __restrict__ VB,
    const unsigned short* __restrict__ WtQ, const unsigned short* __restrict__ WtK,
    const unsigned short* __restrict__ WtV,
    const float* __restrict__ bq, const float* __restrict__ bk,
    const float* __restrict__ bv,
    unsigned short* __restrict__ QW, unsigned short* __restrict__ KW,
    unsigned short* __restrict__ VWT) {
  const int mode = blockIdx.z;
  const unsigned short* A8 = (mode == 0) ? QB : VB;
  const unsigned short* Wt = (mode == 0) ? WtQ : (mode == 1) ? WtK : WtV;
  const float* bias = (mode == 0) ? bq : (mode == 1) ? bk : bv;
  const int n0 = blockIdx.x * 128, m0 = blockIdx.y * 128;
  const int t = threadIdx.x, lane = t & 63, w = t >> 6;
  const int g = lane >> 4, ln = lane & 15;
  const int wm = w >> 1, wn = w & 1;
  __shared__ unsigned short sh[16896];
  unsigned short* As = sh;          // [128][64] linear
  unsigned short* Bs = sh + 8192;   // [128][64] linear
  const int srow = lane >> 3;
  const int scol = (lane & 7) * 8;
  f32x4 acc[4][4] = {};
  for (int kk = 0; kk < 1024; kk += 64) {
    __syncthreads();
#pragma unroll
    for (int p = 0; p < 4; ++p) {
      gload16(&A8[(size_t)(m0 + p * 32 + w * 8 + srow) * 1024 + kk + scol],
              &As[p * 2048 + w * 512]);
      gload16(&Wt[(size_t)(n0 + p * 32 + w * 8 + srow) * 1024 + kk + scol],
              &Bs[p * 2048 + w * 512]);
    }
    __syncthreads();
#pragma unroll
    for (int ks = 0; ks < 2; ++ks) {
      short8 af[4];
#pragma unroll
      for (int fm = 0; fm < 4; ++fm)
        af[fm] = *(const short8*)&As[(wm * 64 + fm * 16 + ln) * 64 + ks * 32 + 8 * g];
#pragma unroll
      for (int fn = 0; fn < 4; ++fn) {
        short8 bfr = *(const short8*)&Bs[(wn * 64 + fn * 16 + ln) * 64 + ks * 32 + 8 * g];
#pragma unroll
        for (int fm = 0; fm < 4; ++fm) acc[fm][fn] = MFMA16(af[fm], bfr, acc[fm][fn]);
      }
    }
  }
  __syncthreads();
  const float scale = (mode == 0) ? 0.125f : 1.0f;
#pragma unroll
  for (int fn = 0; fn < 4; ++fn) {
    float bn = bias[n0 + wn * 64 + fn * 16 + ln];
#pragma unroll
    for (int fm = 0; fm < 4; ++fm) {
#pragma unroll
      for (int r = 0; r < 4; ++r) {
        float val = (acc[fm][fn][r] + bn) * scale;
        sh[(wm * 64 + fm * 16 + 4 * g + r) * 132 + wn * 64 + fn * 16 + ln] = f2bf(val);
      }
    }
  }
  __syncthreads();
  if (mode < 2) {
    unsigned short* OUT = (mode == 0) ? QW : KW;
#pragma unroll
    for (int p = 0; p < 16; ++p) {
      int row = p * 8 + (t >> 5), c4 = (t & 31) * 4;
      *(u16x4*)&OUT[(size_t)(m0 + row) * 1024 + n0 + c4] =
          *(const u16x4*)&sh[row * 132 + c4];
    }
  } else {
    const int b = m0 >> 10, s0 = m0 & 1023;
#pragma unroll
    for (int p = 0; p < 16; ++p) {
#pragma unroll
      for (int qh = 0; qh < 2; ++qh) {
        int hdl = p * 8 + (t >> 5);
        int sl = qh * 64 + (t & 31) * 2;
        unsigned lo = sh[sl * 132 + hdl];
        unsigned hi = sh[(sl + 1) * 132 + hdl];
        int hd = n0 + hdl;
        int h = hd >> 6, d = hd & 63;
        *(unsigned*)&VWT[((size_t)(b * 16 + h) * 64 + d) * 1024 + s0 + sl] =
            lo | (hi << 16);
      }
    }
  }
}

// ---------------------------------------------------------------------------
// Position-bias scores, stripe of 256 j: CB[bh][jl 256][k 1024]
// ---------------------------------------------------------------------------
__global__ __launch_bounds__(256) void k_pbias(
    const unsigned short* __restrict__ QW, const float* __restrict__ pb,
    unsigned short* __restrict__ CB, int jbase) {
  const int kt = blockIdx.x;  // 0..7
  const int jl = blockIdx.y;  // 0..255
  const int j = jbase + jl;
  const int t = threadIdx.x, lane = t & 63, w = t >> 6;
  const int g = lane >> 4, ln = lane & 15;
  const int wm = w >> 1, wn = w & 1;
  __shared__ unsigned short sm[18432];
  unsigned short* a_lds = sm;         // [128 bh][72]
  unsigned short* b_lds = sm + 9216;  // [128 k][72]
#pragma unroll
  for (int p = 0; p < 8; ++p) {
    int i4 = p * 256 + t;
    int row = i4 >> 4, c4 = (i4 & 15) * 4;
    *(u16x4*)&a_lds[row * 72 + c4] =
        *(const u16x4*)&QW[((size_t)(row >> 4) * 1024 + j) * 1024 + (row & 15) * 64 + c4];
  }
#pragma unroll
  for (int p = 0; p < 8; ++p) {
    int i4 = p * 256 + t;
    int row = i4 >> 4, c4 = (i4 & 15) * 4;
    fl4 val = *(const fl4*)&pb[((size_t)j * 1024 + kt * 128 + row) * 64 + c4];
    u16x4 u;
    u[0] = f2bf(val[0]); u[1] = f2bf(val[1]);
    u[2] = f2bf(val[2]); u[3] = f2bf(val[3]);
    *(u16x4*)&b_lds[row * 72 + c4] = u;
  }
  __syncthreads();
  f32x4 acc[4][4] = {};
#pragma unroll
  for (int ks = 0; ks < 2; ++ks) {
    short8 af[4];
#pragma unroll
    for (int fm = 0; fm < 4; ++fm)
      af[fm] = *(const short8*)&a_lds[(wm * 64 + fm * 16 + ln) * 72 + ks * 32 + 8 * g];
#pragma unroll
    for (int fn = 0; fn < 4; ++fn) {
      short8 bfr = *(const short8*)&b_lds[(wn * 64 + fn * 16 + ln) * 72 + ks * 32 + 8 * g];
#pragma unroll
      for (int fm = 0; fm < 4; ++fm) acc[fm][fn] = MFMA16(af[fm], bfr, acc[fm][fn]);
    }
  }
  __syncthreads();
#pragma unroll
  for (int fn = 0; fn < 4; ++fn) {
#pragma unroll
    for (int fm = 0; fm < 4; ++fm) {
#pragma unroll
      for (int r = 0; r < 4; ++r)
        sm[(wm * 64 + fm * 16 + 4 * g + r) * 132 + wn * 64 + fn * 16 + ln] =
            f2bf(acc[fm][fn][r]);
    }
  }
  __syncthreads();
#pragma unroll
  for (int p = 0; p < 16; ++p) {
    int row = p * 8 + (t >> 5), c4 = (t & 31) * 4;
    *(u16x4*)&CB[((size_t)row * 256 + jl) * 1024 + kt * 128 + c4] =
        *(const u16x4*)&sm[row * 132 + c4];
  }
}

// ---------------------------------------------------------------------------
// Flash attention per (b, h, 64-row j-tile in a 256 stripe).
// CB tile staged through LDS; grid (4,16,8)=512 blocks -> 2 blocks/CU.
// ---------------------------------------------------------------------------
__global__ __launch_bounds__(256) void k_attn(
    const unsigned short* __restrict__ QW, const unsigned short* __restrict__ KW,
    const unsigned short* __restrict__ VWT, const unsigned short* __restrict__ CB,
    const int* __restrict__ vmask, unsigned short* __restrict__ OB, int jbase) {
  const int jt = blockIdx.x, h = blockIdx.y, b = blockIdx.z;
  const int t = threadIdx.x, lane = t & 63, w = t >> 6;
  const int g = lane >> 4, ln = lane & 15;
  const int j0 = jbase + jt * 64;  // global j
  const int jl0 = jt * 64;         // stripe-local j
  __shared__ unsigned short lds_k[128 * 72];
  __shared__ unsigned short lds_vt[64 * 136];
  __shared__ unsigned short lds_cb[64 * 132];
  __shared__ unsigned short lds_p[4 * 16 * 136];
  unsigned short* pw = &lds_p[w * (16 * 136)];
  short8 qf[2];
  {
    const size_t qrow = ((size_t)b * 1024 + (j0 + w * 16 + ln)) * 1024 + h * 64;
    qf[0] = *(const short8*)&QW[qrow + 8 * g];
    qf[1] = *(const short8*)&QW[qrow + 32 + 8 * g];
  }
  const size_t cb_base = ((size_t)(b * 16 + h) * 256 + jl0) * 1024;
  f32x4 o_acc[4] = {};
  float m_run[4], l_run[4];
#pragma unroll
  for (int r = 0; r < 4; ++r) { m_run[r] = -1e30f; l_run[r] = 0.f; }

  for (int kt = 0; kt < 8; ++kt) {
    __syncthreads();
#pragma unroll
    for (int p = 0; p < 8; ++p) {
      int i4 = p * 256 + t;
      int row = i4 >> 4, c4 = (i4 & 15) * 4;
      *(u16x4*)&lds_k[row * 72 + c4] =
          *(const u16x4*)&KW[((size_t)b * 1024 + kt * 128 + row) * 1024 + h * 64 + c4];
    }
#pragma unroll
    for (int p = 0; p < 8; ++p) {
      int i4 = p * 256 + t;
      int row = i4 >> 5, c4 = (i4 & 31) * 4;
      *(u16x4*)&lds_vt[row * 136 + c4] =
          *(const u16x4*)&VWT[(((size_t)b * 16 + h) * 64 + row) * 1024 + kt * 128 + c4];
    }
#pragma unroll
    for (int p = 0; p < 8; ++p) {
      int i4 = p * 256 + t;
      int row = i4 >> 5, c4 = (i4 & 31) * 4;
      *(u16x4*)&lds_cb[row * 132 + c4] =
          *(const u16x4*)&CB[cb_base + (size_t)row * 1024 + kt * 128 + c4];
    }
    __syncthreads();
    f32x4 s[8];
#pragma unroll
    for (int fn = 0; fn < 8; ++fn) {
#pragma unroll
      for (int r = 0; r < 4; ++r)
        s[fn][r] = bf2f(lds_cb[(w * 16 + 4 * g + r) * 132 + 16 * fn + ln]);
    }
#pragma unroll
    for (int ks = 0; ks < 2; ++ks) {
#pragma unroll
      for (int fn = 0; fn < 8; ++fn) {
        short8 bfr = *(const short8*)&lds_k[(ln + 16 * fn) * 72 + ks * 32 + 8 * g];
        s[fn] = MFMA16(qf[ks], bfr, s[fn]);
      }
    }
#pragma unroll
    for (int fn = 0; fn < 8; ++fn) {
      int vm = vmask[b * 1024 + kt * 128 + ln + 16 * fn];
      float sub = (1.0f - (float)vm) * 1e12f;
#pragma unroll
      for (int r = 0; r < 4; ++r) s[fn][r] -= sub;
    }
    float mnew[4];
#pragma unroll
    for (int r = 0; r < 4; ++r) {
      mnew[r] = s[0][r];
#pragma unroll
      for (int fn = 1; fn < 8; ++fn) mnew[r] = fmaxf(mnew[r], s[fn][r]);
    }
#pragma unroll
    for (int off = 1; off < 16; off <<= 1) {
#pragma unroll
      for (int r = 0; r < 4; ++r) mnew[r] = fmaxf(mnew[r], __shfl_xor(mnew[r], off, 16));
    }
    float alpha[4], rs[4];
#pragma unroll
    for (int r = 0; r < 4; ++r) {
      float mt = fmaxf(m_run[r], mnew[r]);
      alpha[r] = __expf(m_run[r] - mt);
      m_run[r] = mt;
      rs[r] = 0.f;
    }
#pragma unroll
    for (int fn = 0; fn < 8; ++fn) {
#pragma unroll
      for (int r = 0; r < 4; ++r) {
        float pv = __expf(s[fn][r] - m_run[r]);
        s[fn][r] = pv;
        rs[r] += pv;
      }
    }
#pragma unroll
    for (int off = 1; off < 16; off <<= 1) {
#pragma unroll
      for (int r = 0; r < 4; ++r) rs[r] += __shfl_xor(rs[r], off, 16);
    }
#pragma unroll
    for (int r = 0; r < 4; ++r) l_run[r] = l_run[r] * alpha[r] + rs[r];
#pragma unroll
    for (int fn = 0; fn < 4; ++fn) {
#pragma unroll
      for (int r = 0; r < 4; ++r) o_acc[fn][r] *= alpha[r];
    }
#pragma unroll
    for (int fn = 0; fn < 8; ++fn) {
#pragma unroll
      for (int r = 0; r < 4; ++r)
        pw[(4 * g + r) * 136 + ln + 16 * fn] = f2bf(s[fn][r]);
    }
    asm volatile("s_waitcnt lgkmcnt(0)" ::: "memory");
#pragma unroll
    for (int ks = 0; ks < 4; ++ks) {
      short8 ap = *(const short8*)&pw[ln * 136 + ks * 32 + 8 * g];
#pragma unroll
      for (int fn = 0; fn < 4; ++fn) {
        short8 bv = *(const short8*)&lds_vt[(ln + 16 * fn) * 136 + ks * 32 + 8 * g];
        o_acc[fn] = MFMA16(ap, bv, o_acc[fn]);
      }
    }
  }
#pragma unroll
  for (int r = 0; r < 4; ++r) {
    float inv = 1.0f / l_run[r];
#pragma unroll
    for (int fn = 0; fn < 4; ++fn) o_acc[fn][r] *= inv;
  }
#pragma unroll
  for (int fn = 0; fn < 4; ++fn) {
#pragma unroll
    for (int r = 0; r < 4; ++r)
      pw[(4 * g + r) * 136 + ln + 16 * fn] = f2bf(o_acc[fn][r]);
  }
  asm volatile("s_waitcnt lgkmcnt(0)" ::: "memory");
#pragma unroll
  for (int p = 0; p < 4; ++p) {
    int idx = p * 64 + lane;
    int row = idx >> 4, c4 = (idx & 15) * 4;
    *(u16x4*)&OB[((size_t)b * 1024 + (j0 + w * 16 + row)) * 1024 + h * 64 + c4] =
        *(const u16x4*)&pw[row * 136 + c4];
  }
}

// ---------------------------------------------------------------------------
// Output projection: out = (OB @ Wo + bo) * q_mask  (f32 out)
// ---------------------------------------------------------------------------
__global__ __launch_bounds__(256) void k_out2(
    const unsigned short* __restrict__ OB, const unsigned short* __restrict__ WtO,
    const float* __restrict__ bo, const int* __restrict__ qmask,
    float* __restrict__ out) {
  const int n0 = blockIdx.x * 128, m0 = blockIdx.y * 128;
  const int t = threadIdx.x, lane = t & 63, w = t >> 6;
  const int g = lane >> 4, ln = lane & 15;
  const int wm = w >> 1, wn = w & 1;
  __shared__ unsigned short sh[16384];
  unsigned short* As = sh;
  unsigned short* Bs = sh + 8192;
  const int srow = lane >> 3;
  const int scol = (lane & 7) * 8;
  f32x4 acc[4][4] = {};
  for (int kk = 0; kk < 1024; kk += 64) {
    __syncthreads();
#pragma unroll
    for (int p = 0; p < 4; ++p) {
      gload16(&OB[(size_t)(m0 + p * 32 + w * 8 + srow) * 1024 + kk + scol],
              &As[p * 2048 + w * 512]);
      gload16(&WtO[(size_t)(n0 + p * 32 + w * 8 + srow) * 1024 + kk + scol],
              &Bs[p * 2048 + w * 512]);
    }
    __syncthreads();
#pragma unroll
    for (int ks = 0; ks < 2; ++ks) {
      short8 af[4];
#pragma unroll
      for (int fm = 0; fm < 4; ++fm)
        af[fm] = *(const short8*)&As[(wm * 64 + fm * 16 + ln) * 64 + ks * 32 + 8 * g];
#pragma unroll
      for (int fn = 0; fn < 4; ++fn) {
        short8 bfr = *(const short8*)&Bs[(wn * 64 + fn * 16 + ln) * 64 + ks * 32 + 8 * g];
#pragma unroll
        for (int fm = 0; fm < 4; ++fm) acc[fm][fn] = MFMA16(af[fm], bfr, acc[fm][fn]);
      }
    }
  }
  float bn[4];
#pragma unroll
  for (int fn = 0; fn < 4; ++fn) bn[fn] = bo[n0 + wn * 64 + fn * 16 + ln];
#pragma unroll
  for (int fm = 0; fm < 4; ++fm) {
#pragma unroll
    for (int r = 0; r < 4; ++r) {
      int row = m0 + wm * 64 + fm * 16 + 4 * g + r;
      float qm = (float)qmask[row];
#pragma unroll
      for (int fn = 0; fn < 4; ++fn)
        out[(size_t)row * 1024 + n0 + wn * 64 + fn * 16 + ln] =
            (acc[fm][fn][r] + bn[fn]) * qm;
    }
  }
}

// ---------------------------------------------------------------------------
extern "C" void kernel_launch(void* const* d_in, const int* in_sizes, int n_in,
                              void* d_out, int out_size, void* d_ws, size_t ws_size,
                              hipStream_t stream) {
  const float* q  = (const float*)d_in[0];
  // d_in[1] = k  -- intentionally unused (reference projects K from v)
  const float* v  = (const float*)d_in[2];
  const float* pb = (const float*)d_in[3];
  const float* Wq = (const float*)d_in[4];
  const float* Wk = (const float*)d_in[5];
  const float* Wv = (const float*)d_in[6];
  const float* Wo = (const float*)d_in[7];
  const float* bq = (const float*)d_in[8];
  const float* bk = (const float*)d_in[9];
  const float* bv = (const float*)d_in[10];
  const float* bo = (const float*)d_in[11];
  const int* qm = (const int*)d_in[12];
  const int* vm = (const int*)d_in[13];
  float* out = (float*)d_out;

  unsigned short* ws = (unsigned short*)d_ws;
  const size_t M1 = 1024 * 1024;
  unsigned short* WTQ = ws;
  unsigned short* WTK = WTQ + M1;
  unsigned short* WTV = WTK + M1;
  unsigned short* WTO = WTV + M1;
  unsigned short* QB  = WTO + M1;              // [8192][1024] bf16(q)
  unsigned short* VB  = QB + 8 * M1;           // [8192][1024] bf16(v)
  unsigned short* QW  = VB + 8 * M1;           // [8192][1024], pre-scaled 1/8
  unsigned short* KW  = QW + 8 * M1;
  unsigned short* VWT = KW + 8 * M1;           // [b][h][d][s]
  unsigned short* OB  = VWT + 8 * M1;
  unsigned short* CB  = OB + 8 * M1;           // [bh 128][jl 256][k 1024] stripe (67MB)

  k_wconv4<<<dim3(16, 16, 4), 256, 0, stream>>>(Wq, Wk, Wv, Wo, WTQ, WTK, WTV, WTO);
  k_cvt<<<dim3(4096, 2), 256, 0, stream>>>(q, v, QB, VB);
  k_proj2<<<dim3(8, 64, 3), 256, 0, stream>>>(QB, VB, WTQ, WTK, WTV, bq, bk, bv,
                                              QW, KW, VWT);
  for (int st = 0; st < 4; ++st) {
    k_pbias<<<dim3(8, 256), 256, 0, stream>>>(QW, pb, CB, st * 256);
    k_attn<<<dim3(4, 16, 8), 256, 0, stream>>>(QW, KW, VWT, CB, vm, OB, st * 256);
  }
  k_out2<<<dim3(8, 64), 256, 0, stream>>>(OB, WTO, bo, qm, out);
}

// Round 4
// 390.392 us; speedup vs baseline: 1.4197x; 1.0986x over previous
//
#include <hip/hip_runtime.h>

using short8 = __attribute__((ext_vector_type(8))) short;
using f32x4  = __attribute__((ext_vector_type(4))) float;
using u16x4  = __attribute__((ext_vector_type(4))) unsigned short;
using fl4    = __attribute__((ext_vector_type(4))) float;

#define MFMA16(a, b, c) __builtin_amdgcn_mfma_f32_16x16x32_bf16((a), (b), (c), 0, 0, 0)

static __device__ __forceinline__ unsigned short f2bf(float f) {
  union { float f; unsigned u; } x; x.f = f;
  return (unsigned short)((x.u + 0x7FFFu + ((x.u >> 16) & 1u)) >> 16);
}
static __device__ __forceinline__ float bf2f(unsigned short s) {
  union { unsigned u; float f; } x; x.u = ((unsigned)s) << 16;
  return x.f;
}

// async global->LDS, 16B per lane; lds base must be wave-uniform.
static __device__ __forceinline__ void gload16(const void* g, void* l) {
  __builtin_amdgcn_global_load_lds((const __attribute__((address_space(1))) void*)g,
                                   (__attribute__((address_space(3))) void*)l, 16, 0, 0);
}

// ---------------------------------------------------------------------------
// Wt[n][k] = bf16(W[k][n]) for 4 weight matrices (z picks which)
// ---------------------------------------------------------------------------
__global__ __launch_bounds__(256) void k_wconv4(
    const float* __restrict__ W0, const float* __restrict__ W1,
    const float* __restrict__ W2, const float* __restrict__ W3,
    unsigned short* __restrict__ Wt0, unsigned short* __restrict__ Wt1,
    unsigned short* __restrict__ Wt2, unsigned short* __restrict__ Wt3) {
  const float* W = (blockIdx.z == 0) ? W0 : (blockIdx.z == 1) ? W1
                   : (blockIdx.z == 2) ? W2 : W3;
  unsigned short* Wt = (blockIdx.z == 0) ? Wt0 : (blockIdx.z == 1) ? Wt1
                       : (blockIdx.z == 2) ? Wt2 : Wt3;
  __shared__ float tile[64][65];
  const int t = threadIdx.x;
  const int n0 = blockIdx.x * 64, k0 = blockIdx.y * 64;
#pragma unroll
  for (int p = 0; p < 4; ++p) {
    int row = p * 16 + (t >> 4);
    int c4 = (t & 15) * 4;
    fl4 val = *(const fl4*)&W[(size_t)(k0 + row) * 1024 + n0 + c4];
    tile[row][c4 + 0] = val[0];
    tile[row][c4 + 1] = val[1];
    tile[row][c4 + 2] = val[2];
    tile[row][c4 + 3] = val[3];
  }
  __syncthreads();
#pragma unroll
  for (int p = 0; p < 4; ++p) {
    int n = p * 16 + (t >> 4);
    int k4 = (t & 15) * 4;
    u16x4 u;
    u[0] = f2bf(tile[k4 + 0][n]);
    u[1] = f2bf(tile[k4 + 1][n]);
    u[2] = f2bf(tile[k4 + 2][n]);
    u[3] = f2bf(tile[k4 + 3][n]);
    *(u16x4*)&Wt[(size_t)(n0 + n) * 1024 + k0 + k4] = u;
  }
}

// ---------------------------------------------------------------------------
// f32 -> bf16 bulk convert (q and v)
// ---------------------------------------------------------------------------
__global__ __launch_bounds__(256) void k_cvt(const float* __restrict__ a,
                                             const float* __restrict__ b,
                                             unsigned short* __restrict__ oa,
                                             unsigned short* __restrict__ ob) {
  const float* src = blockIdx.y ? b : a;
  unsigned short* dst = blockIdx.y ? ob : oa;
  size_t i = ((size_t)blockIdx.x * 256 + threadIdx.x) * 8;
  fl4 v0 = *(const fl4*)&src[i];
  fl4 v1 = *(const fl4*)&src[i + 4];
  u16x4 u0, u1;
  u0[0] = f2bf(v0[0]); u0[1] = f2bf(v0[1]); u0[2] = f2bf(v0[2]); u0[3] = f2bf(v0[3]);
  u1[0] = f2bf(v1[0]); u1[1] = f2bf(v1[1]); u1[2] = f2bf(v1[2]); u1[3] = f2bf(v1[3]);
  *(u16x4*)&dst[i] = u0;
  *(u16x4*)&dst[i + 4] = u1;
}

// ---------------------------------------------------------------------------
// m97-style bf16 GEMM for projections. mode: 0=QW(scaled 1/8) 1=KW 2=VWT.
// ---------------------------------------------------------------------------
__global__ __launch_bounds__(256) void k_proj2(
    const unsigned short* __restrict__ QB, const unsigned short* __restrict__ VB,
    const unsigned short* __restrict__ WtQ, const unsigned short* __restrict__ WtK,
    const unsigned short* __restrict__ WtV,
    const float* __restrict__ bq, const float* __restrict__ bk,
    const float* __restrict__ bv,
    unsigned short* __restrict__ QW, unsigned short* __restrict__ KW,
    unsigned short* __restrict__ VWT) {
  const int mode = blockIdx.z;
  const unsigned short* A8 = (mode == 0) ? QB : VB;
  const unsigned short* Wt = (mode == 0) ? WtQ : (mode == 1) ? WtK : WtV;
  const float* bias = (mode == 0) ? bq : (mode == 1) ? bk : bv;
  const int n0 = blockIdx.x * 128, m0 = blockIdx.y * 128;
  const int t = threadIdx.x, lane = t & 63, w = t >> 6;
  const int g = lane >> 4, ln = lane & 15;
  const int wm = w >> 1, wn = w & 1;
  __shared__ unsigned short sh[16896];
  unsigned short* As = sh;          // [128][64] linear
  unsigned short* Bs = sh + 8192;   // [128][64] linear
  const int srow = lane >> 3;
  const int scol = (lane & 7) * 8;
  f32x4 acc[4][4] = {};
  for (int kk = 0; kk < 1024; kk += 64) {
    __syncthreads();
#pragma unroll
    for (int p = 0; p < 4; ++p) {
      gload16(&A8[(size_t)(m0 + p * 32 + w * 8 + srow) * 1024 + kk + scol],
              &As[p * 2048 + w * 512]);
      gload16(&Wt[(size_t)(n0 + p * 32 + w * 8 + srow) * 1024 + kk + scol],
              &Bs[p * 2048 + w * 512]);
    }
    __syncthreads();
#pragma unroll
    for (int ks = 0; ks < 2; ++ks) {
      short8 af[4];
#pragma unroll
      for (int fm = 0; fm < 4; ++fm)
        af[fm] = *(const short8*)&As[(wm * 64 + fm * 16 + ln) * 64 + ks * 32 + 8 * g];
#pragma unroll
      for (int fn = 0; fn < 4; ++fn) {
        short8 bfr = *(const short8*)&Bs[(wn * 64 + fn * 16 + ln) * 64 + ks * 32 + 8 * g];
#pragma unroll
        for (int fm = 0; fm < 4; ++fm) acc[fm][fn] = MFMA16(af[fm], bfr, acc[fm][fn]);
      }
    }
  }
  __syncthreads();
  const float scale = (mode == 0) ? 0.125f : 1.0f;
#pragma unroll
  for (int fn = 0; fn < 4; ++fn) {
    float bn = bias[n0 + wn * 64 + fn * 16 + ln];
#pragma unroll
    for (int fm = 0; fm < 4; ++fm) {
#pragma unroll
      for (int r = 0; r < 4; ++r) {
        float val = (acc[fm][fn][r] + bn) * scale;
        sh[(wm * 64 + fm * 16 + 4 * g + r) * 132 + wn * 64 + fn * 16 + ln] = f2bf(val);
      }
    }
  }
  __syncthreads();
  if (mode < 2) {
    unsigned short* OUT = (mode == 0) ? QW : KW;
#pragma unroll
    for (int p = 0; p < 16; ++p) {
      int row = p * 8 + (t >> 5), c4 = (t & 31) * 4;
      *(u16x4*)&OUT[(size_t)(m0 + row) * 1024 + n0 + c4] =
          *(const u16x4*)&sh[row * 132 + c4];
    }
  } else {
    const int b = m0 >> 10, s0 = m0 & 1023;
#pragma unroll
    for (int p = 0; p < 16; ++p) {
#pragma unroll
      for (int qh = 0; qh < 2; ++qh) {
        int hdl = p * 8 + (t >> 5);
        int sl = qh * 64 + (t & 31) * 2;
        unsigned lo = sh[sl * 132 + hdl];
        unsigned hi = sh[(sl + 1) * 132 + hdl];
        int hd = n0 + hdl;
        int h = hd >> 6, d = hd & 63;
        *(unsigned*)&VWT[((size_t)(b * 16 + h) * 64 + d) * 1024 + s0 + sl] =
            lo | (hi << 16);
      }
    }
  }
}

// ---------------------------------------------------------------------------
// Position-bias scores, stripe of 512 j: CB[bh][jl 512][k 1024]
// Key mask (-1e12 for masked keys) is folded into CB here.
// ---------------------------------------------------------------------------
__global__ __launch_bounds__(256) void k_pbias(
    const unsigned short* __restrict__ QW, const float* __restrict__ pb,
    const int* __restrict__ vmask, unsigned short* __restrict__ CB, int jbase) {
  const int kt = blockIdx.x;  // 0..7
  const int jl = blockIdx.y;  // 0..511
  const int j = jbase + jl;
  const int t = threadIdx.x, lane = t & 63, w = t >> 6;
  const int g = lane >> 4, ln = lane & 15;
  const int wm = w >> 1, wn = w & 1;
  __shared__ unsigned short sm[18432];
  unsigned short* a_lds = sm;         // [128 bh][72]
  unsigned short* b_lds = sm + 9216;  // [128 k][72]
#pragma unroll
  for (int p = 0; p < 8; ++p) {
    int i4 = p * 256 + t;
    int row = i4 >> 4, c4 = (i4 & 15) * 4;
    *(u16x4*)&a_lds[row * 72 + c4] =
        *(const u16x4*)&QW[((size_t)(row >> 4) * 1024 + j) * 1024 + (row & 15) * 64 + c4];
  }
#pragma unroll
  for (int p = 0; p < 8; ++p) {
    int i4 = p * 256 + t;
    int row = i4 >> 4, c4 = (i4 & 15) * 4;
    fl4 val = *(const fl4*)&pb[((size_t)j * 1024 + kt * 128 + row) * 64 + c4];
    u16x4 u;
    u[0] = f2bf(val[0]); u[1] = f2bf(val[1]);
    u[2] = f2bf(val[2]); u[3] = f2bf(val[3]);
    *(u16x4*)&b_lds[row * 72 + c4] = u;
  }
  __syncthreads();
  f32x4 acc[4][4] = {};
#pragma unroll
  for (int ks = 0; ks < 2; ++ks) {
    short8 af[4];
#pragma unroll
    for (int fm = 0; fm < 4; ++fm)
      af[fm] = *(const short8*)&a_lds[(wm * 64 + fm * 16 + ln) * 72 + ks * 32 + 8 * g];
#pragma unroll
    for (int fn = 0; fn < 4; ++fn) {
      short8 bfr = *(const short8*)&b_lds[(wn * 64 + fn * 16 + ln) * 72 + ks * 32 + 8 * g];
#pragma unroll
      for (int fm = 0; fm < 4; ++fm) acc[fm][fn] = MFMA16(af[fm], bfr, acc[fm][fn]);
    }
  }
  __syncthreads();
#pragma unroll
  for (int fn = 0; fn < 4; ++fn) {
    int kcol = kt * 128 + wn * 64 + fn * 16 + ln;
#pragma unroll
    for (int fm = 0; fm < 4; ++fm) {
      // b of output row (bh = wm*64+fm*16+4g+r): b = bh>>4 = wm*4+fm
      float off = vmask[(wm * 4 + fm) * 1024 + kcol] ? 0.f : -1e12f;
#pragma unroll
      for (int r = 0; r < 4; ++r)
        sm[(wm * 64 + fm * 16 + 4 * g + r) * 132 + wn * 64 + fn * 16 + ln] =
            f2bf(acc[fm][fn][r] + off);
    }
  }
  __syncthreads();
#pragma unroll
  for (int p = 0; p < 16; ++p) {
    int row = p * 8 + (t >> 5), c4 = (t & 31) * 4;
    *(u16x4*)&CB[((size_t)row * 512 + jl) * 1024 + kt * 128 + c4] =
        *(const u16x4*)&sm[row * 132 + c4];
  }
}

// ---------------------------------------------------------------------------
// Flash attention, swapped-operand form. Block = (jt, h, b), 4 waves x 16 j.
// Each lane owns one j-row (j = ln). S^T = mfma(K, Q); O^T = mfma(V^T, P^T).
// Fixed-max softmax (exp(s-12), exact). Mask pre-folded into CB.
// ---------------------------------------------------------------------------
__global__ __launch_bounds__(256) void k_attn(
    const unsigned short* __restrict__ QW, const unsigned short* __restrict__ KW,
    const unsigned short* __restrict__ VWT, const unsigned short* __restrict__ CB,
    unsigned short* __restrict__ OB, int jbase) {
  const int jt = blockIdx.x, h = blockIdx.y, b = blockIdx.z;
  const int t = threadIdx.x, lane = t & 63, w = t >> 6;
  const int g = lane >> 4, ln = lane & 15;
  const int j0 = jbase + jt * 64;
  const int jl0 = jt * 64;
  __shared__ unsigned short lds_k[128 * 72];   // [k 128][d 72]
  __shared__ unsigned short lds_vt[64 * 136];  // [d 64][k 136]
  __shared__ unsigned short lds_p[4 * 16 * 136];
  unsigned short* pw = &lds_p[w * (16 * 136)];
  short8 qf[2];
  {
    const size_t qrow = ((size_t)b * 1024 + (j0 + w * 16 + ln)) * 1024 + h * 64;
    qf[0] = *(const short8*)&QW[qrow + 8 * g];
    qf[1] = *(const short8*)&QW[qrow + 32 + 8 * g];
  }
  const size_t cb_row = ((size_t)(b * 16 + h) * 512 + jl0 + w * 16 + ln) * 1024;

  u16x4 rk[8], rv[8], rcb[8];
#define LOAD_KV(kt_)                                                              \
  {                                                                               \
    _Pragma("unroll") for (int p = 0; p < 8; ++p) {                               \
      int i4 = p * 256 + t;                                                       \
      int row = i4 >> 4, c4 = (i4 & 15) * 4;                                      \
      rk[p] = *(const u16x4*)&KW[((size_t)b * 1024 + (kt_) * 128 + row) * 1024 +  \
                                 h * 64 + c4];                                    \
    }                                                                             \
    _Pragma("unroll") for (int p = 0; p < 8; ++p) {                               \
      int i4 = p * 256 + t;                                                       \
      int row = i4 >> 5, c4 = (i4 & 31) * 4;                                      \
      rv[p] = *(const u16x4*)&VWT[(((size_t)b * 16 + h) * 64 + row) * 1024 +      \
                                  (kt_) * 128 + c4];                              \
    }                                                                             \
    _Pragma("unroll") for (int p = 0; p < 8; ++p)                                 \
        rcb[p] = *(const u16x4*)&CB[cb_row + (kt_) * 128 + p * 16 + 4 * g];       \
  }

  LOAD_KV(0);
  f32x4 o_acc[4] = {};
  float l_par = 0.f;

  for (int kt = 0; kt < 8; ++kt) {
    __syncthreads();  // all waves done reading LDS of previous tile
#pragma unroll
    for (int p = 0; p < 8; ++p) {
      int i4 = p * 256 + t;
      int row = i4 >> 4, c4 = (i4 & 15) * 4;
      *(u16x4*)&lds_k[row * 72 + c4] = rk[p];
    }
#pragma unroll
    for (int p = 0; p < 8; ++p) {
      int i4 = p * 256 + t;
      int row = i4 >> 5, c4 = (i4 & 31) * 4;
      *(u16x4*)&lds_vt[row * 136 + c4] = rv[p];
    }
    // S^T init from CB (C-layout: row k = fm*16+4g+r, col j = ln)
    f32x4 s[8];
#pragma unroll
    for (int fm = 0; fm < 8; ++fm) {
#pragma unroll
      for (int r = 0; r < 4; ++r) s[fm][r] = bf2f(rcb[fm][r]);
    }
    if (kt < 7) LOAD_KV(kt + 1);  // prefetch next tile into regs (T14)
    __syncthreads();
    // S^T += K x Q
#pragma unroll
    for (int ks = 0; ks < 2; ++ks) {
#pragma unroll
      for (int fm = 0; fm < 8; ++fm) {
        short8 af = *(const short8*)&lds_k[(fm * 16 + ln) * 72 + ks * 32 + 8 * g];
        s[fm] = MFMA16(af, qf[ks], s[fm]);
      }
    }
    // P = exp(s - 12)  (fixed shift; exact softmax after normalization)
#pragma unroll
    for (int fm = 0; fm < 8; ++fm) {
      u16x4 pp;
#pragma unroll
      for (int r = 0; r < 4; ++r) {
        float pv = __expf(s[fm][r] - 12.0f);
        l_par += pv;
        pp[r] = f2bf(pv);
      }
      *(u16x4*)&pw[ln * 136 + fm * 16 + 4 * g] = pp;  // P^T -> [j=ln][k]
    }
    asm volatile("s_waitcnt lgkmcnt(0)" ::: "memory");
    // O^T += V^T x P^T
#pragma unroll
    for (int ks = 0; ks < 4; ++ks) {
      short8 bp = *(const short8*)&pw[ln * 136 + ks * 32 + 8 * g];
#pragma unroll
      for (int fm = 0; fm < 4; ++fm) {
        short8 av = *(const short8*)&lds_vt[(fm * 16 + ln) * 136 + ks * 32 + 8 * g];
        o_acc[fm] = MFMA16(av, bp, o_acc[fm]);
      }
    }
  }
  // row-sum: lanes with same ln (xor 16, 32) hold the 4 k-quarters of row j
  l_par += __shfl_xor(l_par, 16);
  l_par += __shfl_xor(l_par, 32);
  float inv = 1.0f / l_par;
  const size_t orow = ((size_t)b * 1024 + (j0 + w * 16 + ln)) * 1024 + h * 64;
#pragma unroll
  for (int fm = 0; fm < 4; ++fm) {
    u16x4 uo;
#pragma unroll
    for (int r = 0; r < 4; ++r) uo[r] = f2bf(o_acc[fm][r] * inv);
    *(u16x4*)&OB[orow + fm * 16 + 4 * g] = uo;  // d = fm*16+4g+r
  }
#undef LOAD_KV
}

// ---------------------------------------------------------------------------
// Output projection: out = (OB @ Wo + bo) * q_mask  (f32 out)
// ---------------------------------------------------------------------------
__global__ __launch_bounds__(256) void k_out2(
    const unsigned short* __restrict__ OB, const unsigned short* __restrict__ WtO,
    const float* __restrict__ bo, const int* __restrict__ qmask,
    float* __restrict__ out) {
  const int n0 = blockIdx.x * 128, m0 = blockIdx.y * 128;
  const int t = threadIdx.x, lane = t & 63, w = t >> 6;
  const int g = lane >> 4, ln = lane & 15;
  const int wm = w >> 1, wn = w & 1;
  __shared__ unsigned short sh[16384];
  unsigned short* As = sh;
  unsigned short* Bs = sh + 8192;
  const int srow = lane >> 3;
  const int scol = (lane & 7) * 8;
  f32x4 acc[4][4] = {};
  for (int kk = 0; kk < 1024; kk += 64) {
    __syncthreads();
#pragma unroll
    for (int p = 0; p < 4; ++p) {
      gload16(&OB[(size_t)(m0 + p * 32 + w * 8 + srow) * 1024 + kk + scol],
              &As[p * 2048 + w * 512]);
      gload16(&WtO[(size_t)(n0 + p * 32 + w * 8 + srow) * 1024 + kk + scol],
              &Bs[p * 2048 + w * 512]);
    }
    __syncthreads();
#pragma unroll
    for (int ks = 0; ks < 2; ++ks) {
      short8 af[4];
#pragma unroll
      for (int fm = 0; fm < 4; ++fm)
        af[fm] = *(const short8*)&As[(wm * 64 + fm * 16 + ln) * 64 + ks * 32 + 8 * g];
#pragma unroll
      for (int fn = 0; fn < 4; ++fn) {
        short8 bfr = *(const short8*)&Bs[(wn * 64 + fn * 16 + ln) * 64 + ks * 32 + 8 * g];
#pragma unroll
        for (int fm = 0; fm < 4; ++fm) acc[fm][fn] = MFMA16(af[fm], bfr, acc[fm][fn]);
      }
    }
  }
  float bn[4];
#pragma unroll
  for (int fn = 0; fn < 4; ++fn) bn[fn] = bo[n0 + wn * 64 + fn * 16 + ln];
#pragma unroll
  for (int fm = 0; fm < 4; ++fm) {
#pragma unroll
    for (int r = 0; r < 4; ++r) {
      int row = m0 + wm * 64 + fm * 16 + 4 * g + r;
      float qm = (float)qmask[row];
#pragma unroll
      for (int fn = 0; fn < 4; ++fn)
        out[(size_t)row * 1024 + n0 + wn * 64 + fn * 16 + ln] =
            (acc[fm][fn][r] + bn[fn]) * qm;
    }
  }
}

// ---------------------------------------------------------------------------
extern "C" void kernel_launch(void* const* d_in, const int* in_sizes, int n_in,
                              void* d_out, int out_size, void* d_ws, size_t ws_size,
                              hipStream_t stream) {
  const float* q  = (const float*)d_in[0];
  // d_in[1] = k  -- intentionally unused (reference projects K from v)
  const float* v  = (const float*)d_in[2];
  const float* pb = (const float*)d_in[3];
  const float* Wq = (const float*)d_in[4];
  const float* Wk = (const float*)d_in[5];
  const float* Wv = (const float*)d_in[6];
  const float* Wo = (const float*)d_in[7];
  const float* bq = (const float*)d_in[8];
  const float* bk = (const float*)d_in[9];
  const float* bv = (const float*)d_in[10];
  const float* bo = (const float*)d_in[11];
  const int* qm = (const int*)d_in[12];
  const int* vm = (const int*)d_in[13];
  float* out = (float*)d_out;

  unsigned short* ws = (unsigned short*)d_ws;
  const size_t M1 = 1024 * 1024;
  unsigned short* WTQ = ws;
  unsigned short* WTK = WTQ + M1;
  unsigned short* WTV = WTK + M1;
  unsigned short* WTO = WTV + M1;
  unsigned short* QB  = WTO + M1;              // [8192][1024] bf16(q)
  unsigned short* VB  = QB + 8 * M1;           // [8192][1024] bf16(v)
  unsigned short* QW  = VB + 8 * M1;           // [8192][1024], pre-scaled 1/8
  unsigned short* KW  = QW + 8 * M1;
  unsigned short* VWT = KW + 8 * M1;           // [b][h][d][s]
  unsigned short* OB  = VWT + 8 * M1;
  unsigned short* CB  = OB + 8 * M1;           // [bh 128][jl 512][k 1024] stripe (134MB)

  k_wconv4<<<dim3(16, 16, 4), 256, 0, stream>>>(Wq, Wk, Wv, Wo, WTQ, WTK, WTV, WTO);
  k_cvt<<<dim3(4096, 2), 256, 0, stream>>>(q, v, QB, VB);
  k_proj2<<<dim3(8, 64, 3), 256, 0, stream>>>(QB, VB, WTQ, WTK, WTV, bq, bk, bv,
                                              QW, KW, VWT);
  for (int st = 0; st < 2; ++st) {
    k_pbias<<<dim3(8, 512), 256, 0, stream>>>(QW, pb, vm, CB, st * 512);
    k_attn<<<dim3(8, 16, 8), 256, 0, stream>>>(QW, KW, VWT, CB, OB, st * 512);
  }
  k_out2<<<dim3(8, 64), 256, 0, stream>>>(OB, WTO, bo, qm, out);
}

// Round 6
// 386.449 us; speedup vs baseline: 1.4342x; 1.0102x over previous
//
#include <hip/hip_runtime.h>

using short8 = __attribute__((ext_vector_type(8))) short;
using f32x4  = __attribute__((ext_vector_type(4))) float;
using u16x4  = __attribute__((ext_vector_type(4))) unsigned short;
using fl4    = __attribute__((ext_vector_type(4))) float;

#define MFMA16(a, b, c) __builtin_amdgcn_mfma_f32_16x16x32_bf16((a), (b), (c), 0, 0, 0)

static __device__ __forceinline__ unsigned short f2bf(float f) {
  union { float f; unsigned u; } x; x.f = f;
  return (unsigned short)((x.u + 0x7FFFu + ((x.u >> 16) & 1u)) >> 16);
}
static __device__ __forceinline__ float bf2f(unsigned short s) {
  union { unsigned u; float f; } x; x.u = ((unsigned)s) << 16;
  return x.f;
}
// v_exp_f32 computes 2^x directly (input pre-scaled by log2e upstream)
static __device__ __forceinline__ float fexp2(float x) {
  float r; asm("v_exp_f32 %0, %1" : "=v"(r) : "v"(x)); return r;
}
// packed f32x2 -> bf16x2 (RNE), T12 recipe
static __device__ __forceinline__ unsigned pk2(float lo, float hi) {
  unsigned r; asm("v_cvt_pk_bf16_f32 %0, %1, %2" : "=v"(r) : "v"(lo), "v"(hi));
  return r;
}

// async global->LDS, 16B per lane; lds base must be wave-uniform.
static __device__ __forceinline__ void gload16(const void* g, void* l) {
  __builtin_amdgcn_global_load_lds((const __attribute__((address_space(1))) void*)g,
                                   (__attribute__((address_space(3))) void*)l, 16, 0, 0);
}

#define LOG2E 1.4426950408889634f

// ---------------------------------------------------------------------------
// Wt[n][k] = bf16(W[k][n]) for 4 weight matrices (z picks which)
// ---------------------------------------------------------------------------
__global__ __launch_bounds__(256) void k_wconv4(
    const float* __restrict__ W0, const float* __restrict__ W1,
    const float* __restrict__ W2, const float* __restrict__ W3,
    unsigned short* __restrict__ Wt0, unsigned short* __restrict__ Wt1,
    unsigned short* __restrict__ Wt2, unsigned short* __restrict__ Wt3) {
  const float* W = (blockIdx.z == 0) ? W0 : (blockIdx.z == 1) ? W1
                   : (blockIdx.z == 2) ? W2 : W3;
  unsigned short* Wt = (blockIdx.z == 0) ? Wt0 : (blockIdx.z == 1) ? Wt1
                       : (blockIdx.z == 2) ? Wt2 : Wt3;
  __shared__ float tile[64][65];
  const int t = threadIdx.x;
  const int n0 = blockIdx.x * 64, k0 = blockIdx.y * 64;
#pragma unroll
  for (int p = 0; p < 4; ++p) {
    int row = p * 16 + (t >> 4);
    int c4 = (t & 15) * 4;
    fl4 val = *(const fl4*)&W[(size_t)(k0 + row) * 1024 + n0 + c4];
    tile[row][c4 + 0] = val[0];
    tile[row][c4 + 1] = val[1];
    tile[row][c4 + 2] = val[2];
    tile[row][c4 + 3] = val[3];
  }
  __syncthreads();
#pragma unroll
  for (int p = 0; p < 4; ++p) {
    int n = p * 16 + (t >> 4);
    int k4 = (t & 15) * 4;
    u16x4 u;
    u[0] = f2bf(tile[k4 + 0][n]);
    u[1] = f2bf(tile[k4 + 1][n]);
    u[2] = f2bf(tile[k4 + 2][n]);
    u[3] = f2bf(tile[k4 + 3][n]);
    *(u16x4*)&Wt[(size_t)(n0 + n) * 1024 + k0 + k4] = u;
  }
}

// ---------------------------------------------------------------------------
// f32 -> bf16 bulk convert (q and v)
// ---------------------------------------------------------------------------
__global__ __launch_bounds__(256) void k_cvt(const float* __restrict__ a,
                                             const float* __restrict__ b,
                                             unsigned short* __restrict__ oa,
                                             unsigned short* __restrict__ ob) {
  const float* src = blockIdx.y ? b : a;
  unsigned short* dst = blockIdx.y ? ob : oa;
  size_t i = ((size_t)blockIdx.x * 256 + threadIdx.x) * 8;
  fl4 v0 = *(const fl4*)&src[i];
  fl4 v1 = *(const fl4*)&src[i + 4];
  u16x4 u0, u1;
  u0[0] = f2bf(v0[0]); u0[1] = f2bf(v0[1]); u0[2] = f2bf(v0[2]); u0[3] = f2bf(v0[3]);
  u1[0] = f2bf(v1[0]); u1[1] = f2bf(v1[1]); u1[2] = f2bf(v1[2]); u1[3] = f2bf(v1[3]);
  *(u16x4*)&dst[i] = u0;
  *(u16x4*)&dst[i + 4] = u1;
}

// ---------------------------------------------------------------------------
// 3-deep pipelined bf16 GEMM core: 128x128 tile, BK=32, 3 LDS K-tile buffers.
// RACE-FIX (r6): counted vmcnt is placed BEFORE s_barrier — each wave confirms
// its OWN tile-t gload_lds stages pre-rendezvous, so post-barrier ALL waves'
// tile-t data is visible. Steady state vmcnt(4): tiles t+1,t+2 stay in flight
// across the barrier (T4 counted property). Stage of t+2 after the barrier is
// WAR-safe: that buffer's readers (iter t-1) completed their ds_reads before
// their MFMAs, which precede this barrier.
// LDS chunk-XOR swizzle (key=(row>>1)&3) applied BOTH sides (rule #21):
// pre-swizzled per-lane global source + linear gload_lds dest + swizzled read.
// ---------------------------------------------------------------------------
#define GEMM3_CORE(APTR, BPTR)                                                  \
  const int t = threadIdx.x, lane = t & 63, w = t >> 6;                         \
  const int g = lane >> 4, ln = lane & 15;                                      \
  const int wm = w >> 1, wn = w & 1;                                            \
  __shared__ unsigned short sh[24576]; /* 3 bufs x (A 4096 + B 4096) elems */   \
  const int srow = lane >> 2;                                                   \
  const int sc = (lane & 3) ^ ((lane >> 3) & 3);                                \
  const int rsw = ((ln >> 1) & 3);                                              \
  f32x4 acc[4][4] = {};                                                         \
  _Pragma("unroll") for (int pre = 0; pre < 2; ++pre) {                         \
    _Pragma("unroll") for (int p = 0; p < 2; ++p) {                             \
      gload16(&APTR[(size_t)(m0 + p * 64 + w * 16 + srow) * 1024 + pre * 32 + sc * 8], \
              &sh[pre * 8192 + (p * 64 + w * 16) * 32]);                        \
      gload16(&BPTR[(size_t)(n0 + p * 64 + w * 16 + srow) * 1024 + pre * 32 + sc * 8], \
              &sh[pre * 8192 + 4096 + (p * 64 + w * 16) * 32]);                 \
    }                                                                           \
  }                                                                             \
  int cur = 0;                                                                  \
  for (int tt = 0; tt < 32; ++tt) {                                             \
    if (tt < 31) {                                                              \
      asm volatile("s_waitcnt vmcnt(4)" ::: "memory");                          \
    } else {                                                                    \
      asm volatile("s_waitcnt vmcnt(0)" ::: "memory");                          \
    }                                                                           \
    __builtin_amdgcn_sched_barrier(0);                                          \
    __builtin_amdgcn_s_barrier();                                               \
    __builtin_amdgcn_sched_barrier(0);                                          \
    if (tt < 30) {                                                              \
      int bb = cur + 2; if (bb >= 3) bb -= 3;                                   \
      int kk = (tt + 2) * 32;                                                   \
      _Pragma("unroll") for (int p = 0; p < 2; ++p) {                           \
        gload16(&APTR[(size_t)(m0 + p * 64 + w * 16 + srow) * 1024 + kk + sc * 8], \
                &sh[bb * 8192 + (p * 64 + w * 16) * 32]);                       \
        gload16(&BPTR[(size_t)(n0 + p * 64 + w * 16 + srow) * 1024 + kk + sc * 8], \
                &sh[bb * 8192 + 4096 + (p * 64 + w * 16) * 32]);                \
      }                                                                         \
    }                                                                           \
    const unsigned short* As = &sh[cur * 8192];                                 \
    const unsigned short* Bs = As + 4096;                                       \
    short8 af[4], bfr[4];                                                       \
    _Pragma("unroll") for (int fm = 0; fm < 4; ++fm)                            \
        af[fm] = *(const short8*)&As[(wm * 64 + fm * 16 + ln) * 32 + (g ^ rsw) * 8]; \
    _Pragma("unroll") for (int fn = 0; fn < 4; ++fn)                            \
        bfr[fn] = *(const short8*)&Bs[(wn * 64 + fn * 16 + ln) * 32 + (g ^ rsw) * 8]; \
    _Pragma("unroll") for (int fn = 0; fn < 4; ++fn) {                          \
      _Pragma("unroll") for (int fm = 0; fm < 4; ++fm)                          \
          acc[fm][fn] = MFMA16(af[fm], bfr[fn], acc[fm][fn]);                   \
    }                                                                           \
    cur = (cur == 2) ? 0 : cur + 1;                                             \
  }

// ---------------------------------------------------------------------------
// Projections (pipelined): mode 0=QW (scaled log2e/8), 1=KW, 2=VWT
// ---------------------------------------------------------------------------
__global__ __launch_bounds__(256) void k_proj3(
    const unsigned short* __restrict__ QB, const unsigned short* __restrict__ VB,
    const unsigned short* __restrict__ WtQ, const unsigned short* __restrict__ WtK,
    const unsigned short* __restrict__ WtV,
    const float* __restrict__ bq, const float* __restrict__ bk,
    const float* __restrict__ bv,
    unsigned short* __restrict__ QW, unsigned short* __restrict__ KW,
    unsigned short* __restrict__ VWT) {
  const int mode = blockIdx.z;
  const unsigned short* A8 = (mode == 0) ? QB : VB;
  const unsigned short* Wt = (mode == 0) ? WtQ : (mode == 1) ? WtK : WtV;
  const float* bias = (mode == 0) ? bq : (mode == 1) ? bk : bv;
  const int n0 = blockIdx.x * 128, m0 = blockIdx.y * 128;
  GEMM3_CORE(A8, Wt)
  __syncthreads();
  const float scale = (mode == 0) ? (0.125f * LOG2E) : 1.0f;
#pragma unroll
  for (int fn = 0; fn < 4; ++fn) {
    float bn = bias[n0 + wn * 64 + fn * 16 + ln];
#pragma unroll
    for (int fm = 0; fm < 4; ++fm) {
#pragma unroll
      for (int r = 0; r < 4; ++r) {
        float val = (acc[fm][fn][r] + bn) * scale;
        sh[(wm * 64 + fm * 16 + 4 * g + r) * 132 + wn * 64 + fn * 16 + ln] = f2bf(val);
      }
    }
  }
  __syncthreads();
  if (mode < 2) {
    unsigned short* OUT = (mode == 0) ? QW : KW;
#pragma unroll
    for (int p = 0; p < 16; ++p) {
      int row = p * 8 + (t >> 5), c4 = (t & 31) * 4;
      *(u16x4*)&OUT[(size_t)(m0 + row) * 1024 + n0 + c4] =
          *(const u16x4*)&sh[row * 132 + c4];
    }
  } else {
    const int b = m0 >> 10, s0 = m0 & 1023;
#pragma unroll
    for (int p = 0; p < 16; ++p) {
#pragma unroll
      for (int qh = 0; qh < 2; ++qh) {
        int hdl = p * 8 + (t >> 5);
        int sl = qh * 64 + (t & 31) * 2;
        unsigned lo = sh[sl * 132 + hdl];
        unsigned hi = sh[(sl + 1) * 132 + hdl];
        int hd = n0 + hdl;
        int h = hd >> 6, d = hd & 63;
        *(unsigned*)&VWT[((size_t)(b * 16 + h) * 64 + d) * 1024 + s0 + sl] =
            lo | (hi << 16);
      }
    }
  }
}

// ---------------------------------------------------------------------------
// Output projection (pipelined): out = (OB @ Wo + bo) * q_mask  (f32 out)
// ---------------------------------------------------------------------------
__global__ __launch_bounds__(256) void k_out3(
    const unsigned short* __restrict__ OB, const unsigned short* __restrict__ WtO,
    const float* __restrict__ bo, const int* __restrict__ qmask,
    float* __restrict__ out) {
  const int n0 = blockIdx.x * 128, m0 = blockIdx.y * 128;
  GEMM3_CORE(OB, WtO)
  float bn[4];
#pragma unroll
  for (int fn = 0; fn < 4; ++fn) bn[fn] = bo[n0 + wn * 64 + fn * 16 + ln];
#pragma unroll
  for (int fm = 0; fm < 4; ++fm) {
#pragma unroll
    for (int r = 0; r < 4; ++r) {
      int row = m0 + wm * 64 + fm * 16 + 4 * g + r;
      float qm = (float)qmask[row];
#pragma unroll
      for (int fn = 0; fn < 4; ++fn)
        out[(size_t)row * 1024 + n0 + wn * 64 + fn * 16 + ln] =
            (acc[fm][fn][r] + bn[fn]) * qm;
    }
  }
}

// ---------------------------------------------------------------------------
// Position-bias scores, stripe of 512 j: CB[bh][jl 512][k 1024]
// Key mask (-NEG*log2e for masked keys) folded into CB here.
// ---------------------------------------------------------------------------
__global__ __launch_bounds__(256) void k_pbias(
    const unsigned short* __restrict__ QW, const float* __restrict__ pb,
    const int* __restrict__ vmask, unsigned short* __restrict__ CB, int jbase) {
  const int kt = blockIdx.x;  // 0..7
  const int jl = blockIdx.y;  // 0..511
  const int j = jbase + jl;
  const int t = threadIdx.x, lane = t & 63, w = t >> 6;
  const int g = lane >> 4, ln = lane & 15;
  const int wm = w >> 1, wn = w & 1;
  __shared__ unsigned short sm[18432];
  unsigned short* a_lds = sm;         // [128 bh][72]
  unsigned short* b_lds = sm + 9216;  // [128 k][72]
#pragma unroll
  for (int p = 0; p < 8; ++p) {
    int i4 = p * 256 + t;
    int row = i4 >> 4, c4 = (i4 & 15) * 4;
    *(u16x4*)&a_lds[row * 72 + c4] =
        *(const u16x4*)&QW[((size_t)(row >> 4) * 1024 + j) * 1024 + (row & 15) * 64 + c4];
  }
#pragma unroll
  for (int p = 0; p < 8; ++p) {
    int i4 = p * 256 + t;
    int row = i4 >> 4, c4 = (i4 & 15) * 4;
    fl4 val = *(const fl4*)&pb[((size_t)j * 1024 + kt * 128 + row) * 64 + c4];
    u16x4 u;
    u[0] = f2bf(val[0]); u[1] = f2bf(val[1]);
    u[2] = f2bf(val[2]); u[3] = f2bf(val[3]);
    *(u16x4*)&b_lds[row * 72 + c4] = u;
  }
  __syncthreads();
  f32x4 acc[4][4] = {};
#pragma unroll
  for (int ks = 0; ks < 2; ++ks) {
    short8 af[4];
#pragma unroll
    for (int fm = 0; fm < 4; ++fm)
      af[fm] = *(const short8*)&a_lds[(wm * 64 + fm * 16 + ln) * 72 + ks * 32 + 8 * g];
#pragma unroll
    for (int fn = 0; fn < 4; ++fn) {
      short8 bfr = *(const short8*)&b_lds[(wn * 64 + fn * 16 + ln) * 72 + ks * 32 + 8 * g];
#pragma unroll
      for (int fm = 0; fm < 4; ++fm) acc[fm][fn] = MFMA16(af[fm], bfr, acc[fm][fn]);
    }
  }
  __syncthreads();
#pragma unroll
  for (int fn = 0; fn < 4; ++fn) {
    int kcol = kt * 128 + wn * 64 + fn * 16 + ln;
#pragma unroll
    for (int fm = 0; fm < 4; ++fm) {
      // b of output row (bh = wm*64+fm*16+4g+r): b = bh>>4 = wm*4+fm
      float off = vmask[(wm * 4 + fm) * 1024 + kcol] ? 0.f : (-1e12f * LOG2E);
#pragma unroll
      for (int r = 0; r < 4; ++r)
        sm[(wm * 64 + fm * 16 + 4 * g + r) * 132 + wn * 64 + fn * 16 + ln] =
            f2bf(acc[fm][fn][r] + off);
    }
  }
  __syncthreads();
#pragma unroll
  for (int p = 0; p < 16; ++p) {
    int row = p * 8 + (t >> 5), c4 = (t & 31) * 4;
    *(u16x4*)&CB[((size_t)row * 512 + jl) * 1024 + kt * 128 + c4] =
        *(const u16x4*)&sm[row * 132 + c4];
  }
}

// ---------------------------------------------------------------------------
// Flash attention, swapped-operand form. Block = (jt, h, b), 4 waves x 16 j.
// Each lane owns one j-row (j = ln). S^T = mfma(K, Q); O^T = mfma(V^T, P^T).
// Scores carry log2e; P = 2^(s-17) via raw v_exp_f32. Mask pre-folded in CB.
// ---------------------------------------------------------------------------
__global__ __launch_bounds__(256) void k_attn(
    const unsigned short* __restrict__ QW, const unsigned short* __restrict__ KW,
    const unsigned short* __restrict__ VWT, const unsigned short* __restrict__ CB,
    unsigned short* __restrict__ OB, int jbase) {
  const int jt = blockIdx.x, h = blockIdx.y, b = blockIdx.z;
  const int t = threadIdx.x, lane = t & 63, w = t >> 6;
  const int g = lane >> 4, ln = lane & 15;
  const int j0 = jbase + jt * 64;
  const int jl0 = jt * 64;
  __shared__ unsigned short lds_k[128 * 72];   // [k 128][d 72]
  __shared__ unsigned short lds_vt[64 * 136];  // [d 64][k 136]
  __shared__ unsigned short lds_p[4 * 16 * 136];
  unsigned short* pw = &lds_p[w * (16 * 136)];
  short8 qf[2];
  {
    const size_t qrow = ((size_t)b * 1024 + (j0 + w * 16 + ln)) * 1024 + h * 64;
    qf[0] = *(const short8*)&QW[qrow + 8 * g];
    qf[1] = *(const short8*)&QW[qrow + 32 + 8 * g];
  }
  const size_t cb_row = ((size_t)(b * 16 + h) * 512 + jl0 + w * 16 + ln) * 1024;

  u16x4 rk[8], rv[8], rcb[8];
#define LOAD_KV(kt_)                                                              \
  {                                                                               \
    _Pragma("unroll") for (int p = 0; p < 8; ++p) {                               \
      int i4 = p * 256 + t;                                                       \
      int row = i4 >> 4, c4 = (i4 & 15) * 4;                                      \
      rk[p] = *(const u16x4*)&KW[((size_t)b * 1024 + (kt_) * 128 + row) * 1024 +  \
                                 h * 64 + c4];                                    \
    }                                                                             \
    _Pragma("unroll") for (int p = 0; p < 8; ++p) {                               \
      int i4 = p * 256 + t;                                                       \
      int row = i4 >> 5, c4 = (i4 & 31) * 4;                                      \
      rv[p] = *(const u16x4*)&VWT[(((size_t)b * 16 + h) * 64 + row) * 1024 +      \
                                  (kt_) * 128 + c4];                              \
    }                                                                             \
    _Pragma("unroll") for (int p = 0; p < 8; ++p)                                 \
        rcb[p] = *(const u16x4*)&CB[cb_row + (kt_) * 128 + p * 16 + 4 * g];       \
  }

  LOAD_KV(0);
  f32x4 o_acc[4] = {};
  float l_par = 0.f;

  for (int kt = 0; kt < 8; ++kt) {
    __syncthreads();  // all waves done reading LDS of previous tile
#pragma unroll
    for (int p = 0; p < 8; ++p) {
      int i4 = p * 256 + t;
      int row = i4 >> 4, c4 = (i4 & 15) * 4;
      *(u16x4*)&lds_k[row * 72 + c4] = rk[p];
    }
#pragma unroll
    for (int p = 0; p < 8; ++p) {
      int i4 = p * 256 + t;
      int row = i4 >> 5, c4 = (i4 & 31) * 4;
      *(u16x4*)&lds_vt[row * 136 + c4] = rv[p];
    }
    // S^T init from CB (C-layout: row k = fm*16+4g+r, col j = ln)
    f32x4 s[8];
#pragma unroll
    for (int fm = 0; fm < 8; ++fm) {
#pragma unroll
      for (int r = 0; r < 4; ++r) s[fm][r] = bf2f(rcb[fm][r]);
    }
    if (kt < 7) LOAD_KV(kt + 1);  // prefetch next tile into regs (T14)
    __syncthreads();
    // S^T += K x Q
#pragma unroll
    for (int ks = 0; ks < 2; ++ks) {
#pragma unroll
      for (int fm = 0; fm < 8; ++fm) {
        short8 af = *(const short8*)&lds_k[(fm * 16 + ln) * 72 + ks * 32 + 8 * g];
        s[fm] = MFMA16(af, qf[ks], s[fm]);
      }
    }
    // P = 2^(s - 17)  (fixed shift; exact softmax after normalization)
#pragma unroll
    for (int fm = 0; fm < 8; ++fm) {
      float pv0 = fexp2(s[fm][0] - 17.0f);
      float pv1 = fexp2(s[fm][1] - 17.0f);
      float pv2 = fexp2(s[fm][2] - 17.0f);
      float pv3 = fexp2(s[fm][3] - 17.0f);
      l_par += (pv0 + pv1) + (pv2 + pv3);
      union { u16x4 v; unsigned u[2]; } pp;
      pp.u[0] = pk2(pv0, pv1);
      pp.u[1] = pk2(pv2, pv3);
      *(u16x4*)&pw[ln * 136 + fm * 16 + 4 * g] = pp.v;  // P^T -> [j=ln][k]
    }
    asm volatile("s_waitcnt lgkmcnt(0)" ::: "memory");
    // O^T += V^T x P^T
#pragma unroll
    for (int ks = 0; ks < 4; ++ks) {
      short8 bp = *(const short8*)&pw[ln * 136 + ks * 32 + 8 * g];
#pragma unroll
      for (int fm = 0; fm < 4; ++fm) {
        short8 av = *(const short8*)&lds_vt[(fm * 16 + ln) * 136 + ks * 32 + 8 * g];
        o_acc[fm] = MFMA16(av, bp, o_acc[fm]);
      }
    }
  }
  // row-sum: lanes with same ln (xor 16, 32) hold the 4 k-quarters of row j
  l_par += __shfl_xor(l_par, 16);
  l_par += __shfl_xor(l_par, 32);
  float inv = 1.0f / l_par;
  const size_t orow = ((size_t)b * 1024 + (j0 + w * 16 + ln)) * 1024 + h * 64;
#pragma unroll
  for (int fm = 0; fm < 4; ++fm) {
    union { u16x4 v; unsigned u[2]; } uo;
    uo.u[0] = pk2(o_acc[fm][0] * inv, o_acc[fm][1] * inv);
    uo.u[1] = pk2(o_acc[fm][2] * inv, o_acc[fm][3] * inv);
    *(u16x4*)&OB[orow + fm * 16 + 4 * g] = uo.v;  // d = fm*16+4g+r
  }
#undef LOAD_KV
}

// ---------------------------------------------------------------------------
extern "C" void kernel_launch(void* const* d_in, const int* in_sizes, int n_in,
                              void* d_out, int out_size, void* d_ws, size_t ws_size,
                              hipStream_t stream) {
  const float* q  = (const float*)d_in[0];
  // d_in[1] = k  -- intentionally unused (reference projects K from v)
  const float* v  = (const float*)d_in[2];
  const float* pb = (const float*)d_in[3];
  const float* Wq = (const float*)d_in[4];
  const float* Wk = (const float*)d_in[5];
  const float* Wv = (const float*)d_in[6];
  const float* Wo = (const float*)d_in[7];
  const float* bq = (const float*)d_in[8];
  const float* bk = (const float*)d_in[9];
  const float* bv = (const float*)d_in[10];
  const float* bo = (const float*)d_in[11];
  const int* qm = (const int*)d_in[12];
  const int* vm = (const int*)d_in[13];
  float* out = (float*)d_out;

  unsigned short* ws = (unsigned short*)d_ws;
  const size_t M1 = 1024 * 1024;
  unsigned short* WTQ = ws;
  unsigned short* WTK = WTQ + M1;
  unsigned short* WTV = WTK + M1;
  unsigned short* WTO = WTV + M1;
  unsigned short* QB  = WTO + M1;              // [8192][1024] bf16(q)
  unsigned short* VB  = QB + 8 * M1;           // [8192][1024] bf16(v)
  unsigned short* QW  = VB + 8 * M1;           // [8192][1024], scaled log2e/8
  unsigned short* KW  = QW + 8 * M1;
  unsigned short* VWT = KW + 8 * M1;           // [b][h][d][s]
  unsigned short* OB  = VWT + 8 * M1;
  unsigned short* CB  = OB + 8 * M1;           // [bh 128][jl 512][k 1024] stripe (134MB)

  k_wconv4<<<dim3(16, 16, 4), 256, 0, stream>>>(Wq, Wk, Wv, Wo, WTQ, WTK, WTV, WTO);
  k_cvt<<<dim3(4096, 2), 256, 0, stream>>>(q, v, QB, VB);
  k_proj3<<<dim3(8, 64, 3), 256, 0, stream>>>(QB, VB, WTQ, WTK, WTV, bq, bk, bv,
                                              QW, KW, VWT);
  for (int st = 0; st < 2; ++st) {
    k_pbias<<<dim3(8, 512), 256, 0, stream>>>(QW, pb, vm, CB, st * 512);
    k_attn<<<dim3(8, 16, 8), 256, 0, stream>>>(QW, KW, VWT, CB, OB, st * 512);
  }
  k_out3<<<dim3(8, 64), 256, 0, stream>>>(OB, WTO, bo, qm, out);
}